// Round 3
// baseline (1105.857 us; speedup 1.0000x reference)
//
#include <hip/hip_runtime.h>
#include <hip/hip_bf16.h>

typedef __bf16 bf16_t;
typedef __bf16 bf16x8 __attribute__((ext_vector_type(8)));
typedef float f32x4 __attribute__((ext_vector_type(4)));

#define B_    4
#define LQ_   13343
#define D_    256
#define H_    8
#define HD_   32
#define DFF_  2048
#define M_    (B_ * LQ_)   // 53372 tokens = 4 * 13343 exactly
#define MC_   13343        // M-chunk for FFN (hidden chunk fits Areg+Creg)

// bijective XCD-chunk swizzle (m204): contiguous wgid ranges per XCD
__device__ __forceinline__ int xcd_swz(int orig, int nwg) {
  int q = nwg >> 3, r = nwg & 7;
  int xcd = orig & 7, idx = orig >> 3;
  return (xcd < r ? xcd * (q + 1) : r * (q + 1) + (xcd - r) * q) + idx;
}

// ---------------- GEMM: C = A[M,K] @ Bt[N,K]^T + bias ----------------
#define BM 128
#define BN 128
#define BK 32
// LDS layout LINEAR [128][32] (64 B rows) — required by global_load_lds.

#define MODE_F32       0
#define MODE_F32_ACC   1
#define MODE_BF16      2
#define MODE_BF16_RELU 3

__device__ __forceinline__ void gload_lds16(const void* g, void* l) {
  __builtin_amdgcn_global_load_lds(
      (const __attribute__((address_space(1))) void*)g,
      (__attribute__((address_space(3))) void*)l, 16, 0, 0);
}

template <int MODE, bool AF32>
__global__ __launch_bounds__(256) void gemm_bt(
    const void* __restrict__ Av, int lda,
    const bf16_t* __restrict__ Bt, int ldb,
    const float* __restrict__ bias,
    void* __restrict__ Cv, int ldc,
    int M, int N, int K)
{
  __shared__ alignas(16) bf16_t As[BM * BK];   // 8 KB linear [128][32]
  __shared__ alignas(16) bf16_t Bs[BN * BK];   // 8 KB
  const int tid  = threadIdx.x;
  const int wave = tid >> 6, lane = tid & 63;
  const int m0 = blockIdx.x * BM;
  const int n0 = blockIdx.y * BN;
  const int wm = (wave & 1) * 64;
  const int wn = (wave >> 1) * 64;
  const int lrow = lane & 15;
  const int quad = lane >> 4;

  f32x4 acc[4][4] = {};

  const int srow = wave * 16 + (lane >> 2);
  const int scol = (lane & 3) * 8;
  const bf16_t* Ab = (const bf16_t*)Av;

  const int ar0 = min(m0 + srow,      M - 1);
  const int ar1 = min(m0 + srow + 64, M - 1);
  const int br0 = min(n0 + srow,      N - 1);
  const int br1 = min(n0 + srow + 64, N - 1);

  const int r0 = tid >> 2;          // reg-staging geometry (AF32 path)
  const int kc = (tid & 3) * 8;     // ds_write byte = tid*16, conflict-free

  for (int kt = 0; kt < K; kt += BK) {
    bf16x8 a0 = {}, a1 = {};
    if (AF32) {
      const float* Af = (const float*)Av;
      int gm0 = m0 + r0, gm1 = m0 + r0 + 64;
      if (gm0 < M) {
        const f32x4* p = (const f32x4*)(Af + (size_t)gm0 * lda + kt + kc);
        f32x4 u = p[0], w = p[1];
#pragma unroll
        for (int j = 0; j < 4; ++j) { a0[j] = (bf16_t)u[j]; a0[j + 4] = (bf16_t)w[j]; }
      }
      if (gm1 < M) {
        const f32x4* p = (const f32x4*)(Af + (size_t)gm1 * lda + kt + kc);
        f32x4 u = p[0], w = p[1];
#pragma unroll
        for (int j = 0; j < 4; ++j) { a1[j] = (bf16_t)u[j]; a1[j + 4] = (bf16_t)w[j]; }
      }
    }
    __syncthreads();
    if (AF32) {
      *(bf16x8*)(&As[r0 * BK + kc])        = a0;
      *(bf16x8*)(&As[(r0 + 64) * BK + kc]) = a1;
    } else {
      gload_lds16(Ab + (size_t)ar0 * lda + kt + scol, &As[wave * 512]);
      gload_lds16(Ab + (size_t)ar1 * lda + kt + scol, &As[2048 + wave * 512]);
    }
    gload_lds16(Bt + (size_t)br0 * ldb + kt + scol, &Bs[wave * 512]);
    gload_lds16(Bt + (size_t)br1 * ldb + kt + scol, &Bs[2048 + wave * 512]);
    __syncthreads();

    bf16x8 af[4], bfr[4];
#pragma unroll
    for (int i = 0; i < 4; ++i)
      af[i] = *(const bf16x8*)(&As[(wm + i * 16 + lrow) * BK + quad * 8]);
#pragma unroll
    for (int j = 0; j < 4; ++j)
      bfr[j] = *(const bf16x8*)(&Bs[(wn + j * 16 + lrow) * BK + quad * 8]);
#pragma unroll
    for (int i = 0; i < 4; ++i)
#pragma unroll
      for (int j = 0; j < 4; ++j)
        acc[i][j] = __builtin_amdgcn_mfma_f32_16x16x32_bf16(af[i], bfr[j], acc[i][j], 0, 0, 0);
  }

  float*  Cf = (float*)Cv;
  bf16_t* Cb = (bf16_t*)Cv;
#pragma unroll
  for (int i = 0; i < 4; ++i) {
#pragma unroll
    for (int j = 0; j < 4; ++j) {
      int gn = n0 + wn + j * 16 + lrow;
      if (gn >= N) continue;
      float bv = bias ? bias[gn] : 0.f;
#pragma unroll
      for (int r = 0; r < 4; ++r) {
        int gm = m0 + wm + i * 16 + quad * 4 + r;
        if (gm >= M) continue;
        float v = acc[i][j][r] + bv;
        size_t ci = (size_t)gm * ldc + gn;
        if (MODE == MODE_F32)          Cf[ci] = v;
        else if (MODE == MODE_F32_ACC) Cf[ci] += v;
        else if (MODE == MODE_BF16)    Cb[ci] = (bf16_t)v;
        else                           Cb[ci] = (bf16_t)(v > 0.f ? v : 0.f);
      }
    }
  }
}

// ---- merged offset+attn GEMM: A = (src+pos) inline; N=480 split epilogue ----
// cols 0..319 -> offb bf16 [M,320]; cols 320..479 -> attnb f32 [M,160]
__global__ __launch_bounds__(256) void gemm_qkv(
    const float* __restrict__ src, const float* __restrict__ pos,
    const bf16_t* __restrict__ Bt,     // wTqkv [480][256]
    const float* __restrict__ b_off, const float* __restrict__ b_attn,
    bf16_t* __restrict__ offb, float* __restrict__ attnb)
{
  __shared__ alignas(16) bf16_t As[BM * BK];
  __shared__ alignas(16) bf16_t Bs[BN * BK];
  const int tid  = threadIdx.x;
  const int wave = tid >> 6, lane = tid & 63;
  const int m0 = blockIdx.x * BM;
  const int n0 = blockIdx.y * BN;
  const int wm = (wave & 1) * 64;
  const int wn = (wave >> 1) * 64;
  const int lrow = lane & 15;
  const int quad = lane >> 4;
  const int N = 480;

  f32x4 acc[4][4] = {};

  const int srow = wave * 16 + (lane >> 2);
  const int scol = (lane & 3) * 8;
  const int br0 = min(n0 + srow,      N - 1);
  const int br1 = min(n0 + srow + 64, N - 1);
  const int r0 = tid >> 2;
  const int kc = (tid & 3) * 8;

  for (int kt = 0; kt < 256; kt += BK) {
    bf16x8 a0 = {}, a1 = {};
    int gm0 = m0 + r0, gm1 = m0 + r0 + 64;
    if (gm0 < M_) {
      const f32x4* ps = (const f32x4*)(src + (size_t)gm0 * 256 + kt + kc);
      const f32x4* pp = (const f32x4*)(pos + (size_t)gm0 * 256 + kt + kc);
      f32x4 u = ps[0] + pp[0], w = ps[1] + pp[1];
#pragma unroll
      for (int j = 0; j < 4; ++j) { a0[j] = (bf16_t)u[j]; a0[j + 4] = (bf16_t)w[j]; }
    }
    if (gm1 < M_) {
      const f32x4* ps = (const f32x4*)(src + (size_t)gm1 * 256 + kt + kc);
      const f32x4* pp = (const f32x4*)(pos + (size_t)gm1 * 256 + kt + kc);
      f32x4 u = ps[0] + pp[0], w = ps[1] + pp[1];
#pragma unroll
      for (int j = 0; j < 4; ++j) { a1[j] = (bf16_t)u[j]; a1[j + 4] = (bf16_t)w[j]; }
    }
    __syncthreads();
    *(bf16x8*)(&As[r0 * BK + kc])        = a0;
    *(bf16x8*)(&As[(r0 + 64) * BK + kc]) = a1;
    gload_lds16(Bt + (size_t)br0 * 256 + kt + scol, &Bs[wave * 512]);
    gload_lds16(Bt + (size_t)br1 * 256 + kt + scol, &Bs[2048 + wave * 512]);
    __syncthreads();

    bf16x8 af[4], bfr[4];
#pragma unroll
    for (int i = 0; i < 4; ++i)
      af[i] = *(const bf16x8*)(&As[(wm + i * 16 + lrow) * BK + quad * 8]);
#pragma unroll
    for (int j = 0; j < 4; ++j)
      bfr[j] = *(const bf16x8*)(&Bs[(wn + j * 16 + lrow) * BK + quad * 8]);
#pragma unroll
    for (int i = 0; i < 4; ++i)
#pragma unroll
      for (int j = 0; j < 4; ++j)
        acc[i][j] = __builtin_amdgcn_mfma_f32_16x16x32_bf16(af[i], bfr[j], acc[i][j], 0, 0, 0);
  }

#pragma unroll
  for (int i = 0; i < 4; ++i) {
#pragma unroll
    for (int j = 0; j < 4; ++j) {
      int gn = n0 + wn + j * 16 + lrow;
      if (gn >= N) continue;
      float bv = (gn < 320) ? b_off[gn] : b_attn[gn - 320];
#pragma unroll
      for (int r = 0; r < 4; ++r) {
        int gm = m0 + wm + i * 16 + quad * 4 + r;
        if (gm >= M_) continue;
        float v = acc[i][j][r] + bv;
        if (gn < 320) offb[(size_t)gm * 320 + gn] = (bf16_t)v;
        else          attnb[(size_t)gm * 160 + gn - 320] = v;
      }
    }
  }
}

// ---------------- small kernels ----------------
// one-launch merged coalesced transpose for all 6 weights
__global__ __launch_bounds__(256) void k_transpose_all(
    const float* __restrict__ i0, const float* __restrict__ i1,
    const float* __restrict__ i2, const float* __restrict__ i3,
    const float* __restrict__ i4, const float* __restrict__ i5,
    bf16_t* __restrict__ o0, bf16_t* __restrict__ o1, bf16_t* __restrict__ o2,
    bf16_t* __restrict__ o3, bf16_t* __restrict__ o4, bf16_t* __restrict__ o5)
{
  int bid = blockIdx.x;
  const float* in; bf16_t* out; int K, N, txn;
  if (bid < 80)        { in = i0; out = o0; K = 256;  N = 320;  txn = 10; }
  else if (bid < 120)  { in = i1; out = o1; K = 256;  N = 160;  bid -= 80;  txn = 5; }
  else if (bid < 184)  { in = i2; out = o2; K = 256;  N = 256;  bid -= 120; txn = 8; }
  else if (bid < 248)  { in = i3; out = o3; K = 256;  N = 256;  bid -= 184; txn = 8; }
  else if (bid < 760)  { in = i4; out = o4; K = 256;  N = 2048; bid -= 248; txn = 64; }
  else                 { in = i5; out = o5; K = 2048; N = 256;  bid -= 760; txn = 8; }
  const int bx = bid % txn, by = bid / txn;
  __shared__ float tile[32][33];
  const int k0 = by * 32, n0 = bx * 32;
  const int tx = threadIdx.x & 31, ty = threadIdx.x >> 5;
#pragma unroll
  for (int r = ty; r < 32; r += 8)
    tile[r][tx] = in[(size_t)(k0 + r) * N + n0 + tx];
  __syncthreads();
#pragma unroll
  for (int r = ty; r < 32; r += 8)
    out[(size_t)(n0 + r) * K + k0 + tx] = (bf16_t)tile[tx][r];
}

__global__ void k_softmax20(float* __restrict__ a, int rows) {
  int r = blockIdx.x * blockDim.x + threadIdx.x;
  if (r >= rows) return;
  float* p = a + (size_t)r * 20;
  float mx = p[0];
#pragma unroll
  for (int i = 1; i < 20; ++i) mx = fmaxf(mx, p[i]);
  float e[20], s = 0.f;
#pragma unroll
  for (int i = 0; i < 20; ++i) { e[i] = expf(p[i] - mx); s += e[i]; }
  float inv = 1.f / s;
#pragma unroll
  for (int i = 0; i < 20; ++i) p[i] = e[i] * inv;
}

// 32 queries/block, 1 thread per (q,h): weight math computed once per (q,h),
// off/attn read as contiguous 80B per thread (coalesced across wave).
// XCD-chunked block swizzle keeps neighboring queries on one XCD's L2.
__global__ __launch_bounds__(256) void k_sample(
    const bf16_t* __restrict__ value,   // [B*LQ, 256]
    const bf16_t* __restrict__ off,     // [M, 320]
    const float* __restrict__ attn,     // [M, 160] post-softmax
    const float* __restrict__ rp,       // [M, 10]
    bf16_t* __restrict__ core)          // [M, 256]
{
  const int Wl[5] = {100, 50, 25, 13, 7};
  const int st[5] = {0, 10000, 12500, 13125, 13294};
  const int nwg = (M_ + 31) / 32;                 // 1668
  const int blk = xcd_swz(blockIdx.x, nwg);
  const int bq0 = blk * 32;
  const int t = threadIdx.x;
  const int ql = t >> 3, h = t & 7;
  const int bq = bq0 + ql;

  __shared__ float s_rp[32][10];
  for (int i = t; i < 320; i += 256) {
    int q = i / 10, e = i - q * 10;
    if (bq0 + q < M_) s_rp[q][e] = rp[(size_t)(bq0 + q) * 10 + e];
  }
  __syncthreads();
  if (bq >= M_) return;

  bf16x8 offv[5];
  f32x4  attv[5];
  const bf16_t* op = off  + (size_t)bq * 320 + h * 40;
  const float*  ap = attn + (size_t)bq * 160 + h * 20;
#pragma unroll
  for (int i = 0; i < 5; ++i) offv[i] = *(const bf16x8*)(op + i * 8);
#pragma unroll
  for (int i = 0; i < 5; ++i) attv[i] = *(const f32x4*)(ap + i * 4);

  const int b = bq / LQ_;
  const bf16_t* vbase = value + ((size_t)b * LQ_) * 256 + h * 32;

  float acc[32] = {};
#pragma unroll
  for (int lvl = 0; lvl < 5; ++lvl) {
    const float W = (float)Wl[lvl];
    const float rx = s_rp[ql][lvl * 2], ry = s_rp[ql][lvl * 2 + 1];
#pragma unroll
    for (int p = 0; p < 4; ++p) {
      const int pi = lvl * 4 + p;                       // 0..19, compile-time
      float px = rx * W + (float)offv[pi >> 2][(pi & 3) * 2]     - 0.5f;
      float py = ry * W + (float)offv[pi >> 2][(pi & 3) * 2 + 1] - 0.5f;
      float aw = attv[pi >> 2][pi & 3];
      float x0f = floorf(px), y0f = floorf(py);
      float wx1 = px - x0f, wy1 = py - y0f;
      int x0 = (int)x0f, y0 = (int)y0f;
#pragma unroll
      for (int dy = 0; dy < 2; ++dy) {
        int yi = y0 + dy;
        bool vy = (yi >= 0) & (yi < Wl[lvl]);
        int yc = min(max(yi, 0), Wl[lvl] - 1);
        float wy = dy ? wy1 : 1.f - wy1;
#pragma unroll
        for (int dx = 0; dx < 2; ++dx) {
          int xi = x0 + dx;
          bool vx = (xi >= 0) & (xi < Wl[lvl]);
          int xc = min(max(xi, 0), Wl[lvl] - 1);
          float cw = (vx & vy) ? aw * wy * (dx ? wx1 : 1.f - wx1) : 0.f;
          const bf16_t* vp = vbase + (size_t)(st[lvl] + yc * Wl[lvl] + xc) * 256;
          bf16x8 v0 = *(const bf16x8*)(vp);
          bf16x8 v1 = *(const bf16x8*)(vp + 8);
          bf16x8 v2 = *(const bf16x8*)(vp + 16);
          bf16x8 v3 = *(const bf16x8*)(vp + 24);
#pragma unroll
          for (int j = 0; j < 8; ++j) {
            acc[j]      += cw * (float)v0[j];
            acc[8 + j]  += cw * (float)v1[j];
            acc[16 + j] += cw * (float)v2[j];
            acc[24 + j] += cw * (float)v3[j];
          }
        }
      }
    }
  }
  bf16_t* cp = core + (size_t)bq * 256 + h * 32;
#pragma unroll
  for (int v = 0; v < 4; ++v) {
    bf16x8 o;
#pragma unroll
    for (int j = 0; j < 8; ++j) o[j] = (bf16_t)acc[v * 8 + j];
    *(bf16x8*)(cp + v * 8) = o;
  }
}

// out = LN(a + res [+ eb]) * g + beta ; one row per wave, 4 rows/block
template <typename TA, typename TR, typename TO>
__global__ __launch_bounds__(256) void k_ln4(
    const TA* __restrict__ a, const TR* __restrict__ res,
    const float* __restrict__ eb, const float* __restrict__ g,
    const float* __restrict__ beta, TO* __restrict__ out, int rows)
{
  const int wave = threadIdx.x >> 6, lane = threadIdx.x & 63;
  const int row = blockIdx.x * 4 + wave;
  if (row >= rows) return;
  const size_t base = (size_t)row * 256 + lane * 4;
  float v[4];
#pragma unroll
  for (int j = 0; j < 4; ++j) {
    v[j] = (float)a[base + j] + (float)res[base + j];
    if (eb) v[j] += eb[lane * 4 + j];
  }
  float s1 = v[0] + v[1] + v[2] + v[3];
  float s2 = v[0] * v[0] + v[1] * v[1] + v[2] * v[2] + v[3] * v[3];
#pragma unroll
  for (int o = 32; o > 0; o >>= 1) { s1 += __shfl_xor(s1, o); s2 += __shfl_xor(s2, o); }
  float m = s1 * (1.f / 256.f);
  float var = s2 * (1.f / 256.f) - m * m;
  float inv = rsqrtf(var + 1e-5f);
#pragma unroll
  for (int j = 0; j < 4; ++j)
    out[base + j] = (TO)(((v[j] - m) * inv) * g[lane * 4 + j] + beta[lane * 4 + j]);
}

// ---------------- launcher ----------------
extern "C" void kernel_launch(void* const* d_in, const int* in_sizes, int n_in,
                              void* d_out, int out_size, void* d_ws, size_t ws_size,
                              hipStream_t stream) {
  const float* src   = (const float*)d_in[0];
  const float* pos   = (const float*)d_in[1];
  const float* rp    = (const float*)d_in[2];
  const float* W_off = (const float*)d_in[5];
  const float* b_off = (const float*)d_in[6];
  const float* W_attn= (const float*)d_in[7];
  const float* b_attn= (const float*)d_in[8];
  const float* W_val = (const float*)d_in[9];
  const float* b_val = (const float*)d_in[10];
  const float* W_out = (const float*)d_in[11];
  const float* b_out = (const float*)d_in[12];
  const float* g1    = (const float*)d_in[13];
  const float* beta1 = (const float*)d_in[14];
  const float* W1    = (const float*)d_in[15];
  const float* bl1   = (const float*)d_in[16];
  const float* W2    = (const float*)d_in[17];
  const float* bl2   = (const float*)d_in[18];
  const float* g2    = (const float*)d_in[19];
  const float* beta2 = (const float*)d_in[20];

  char* ws = (char*)d_ws;
  const size_t SZ_TOK = (size_t)M_ * 256 * 2;  // 27,326,464
  const size_t SZ_ATT = (size_t)M_ * 160 * 4;  // 34,158,080

  size_t o = 0;
  bf16_t* wTqkv = (bf16_t*)(ws + o); o += 480 * 256 * 2;   // off rows 0..319, attn 320..479
  bf16_t* wTval = (bf16_t*)(ws + o); o += 256 * 256 * 2;
  bf16_t* wTout = (bf16_t*)(ws + o); o += 256 * 256 * 2;
  bf16_t* wT1   = (bf16_t*)(ws + o); o += 2048 * 256 * 2;
  bf16_t* wT2   = (bf16_t*)(ws + o); o += 2048 * 256 * 2;
  o = (o + 255) & ~(size_t)255;
  char* Areg = ws + o; o += SZ_TOK;   // coreb; FFN: hidden chunk starts here
  char* Creg = ws + o; o += SZ_ATT;   // attnb -> attn_out (contiguous after Areg)
  char* Dreg = ws + o; o += SZ_TOK;   // valb -> xbuf
  size_t base = o;                    // ~91.4MB

  const bool bigws = (ws_size >= base + (size_t)M_ * 2048 * 2);
  bf16_t* hiddenF = (bf16_t*)(ws + base);   // full [M,2048] (big tier only)
  bf16_t* hiddenC = (bf16_t*)Areg;          // chunk [MC_,2048] = 54.65MB <= 61.5MB

  bf16_t* coreb   = (bf16_t*)Areg;
  float*  attnb   = (float*) Creg;
  bf16_t* attn_out= (bf16_t*)Creg;
  bf16_t* valb    = (bf16_t*)Dreg;
  bf16_t* xbuf    = (bf16_t*)Dreg;
  bf16_t* offb    = (bf16_t*)d_out;   // dead before FFN writes outf
  float*  outf    = (float*) d_out;

  k_transpose_all<<<dim3(1272), 256, 0, stream>>>(
      W_off, W_attn, W_val, W_out, W1, W2,
      wTqkv, wTqkv + 320 * 256, wTval, wTout, wT1, wT2);

  dim3 blk(256);
  const int gM = (M_ + BM - 1) / BM;   // 417

  gemm_qkv<<<dim3(gM, 4), blk, 0, stream>>>(src, pos, wTqkv, b_off, b_attn, offb, attnb);
  k_softmax20<<<dim3((M_ * H_ + 255) / 256), 256, 0, stream>>>(attnb, M_ * H_);
  gemm_bt<MODE_BF16, true><<<dim3(gM, 2), blk, 0, stream>>>(src, 256, wTval, 256, b_val, valb, 256, M_, 256, 256);
  k_sample<<<dim3((M_ + 31) / 32), blk, 0, stream>>>(valb, offb, attnb, rp, coreb);
  gemm_bt<MODE_BF16, false><<<dim3(gM, 2), blk, 0, stream>>>(coreb, 256, wTout, 256, b_out, attn_out, 256, M_, 256, 256);
  k_ln4<float, bf16_t, bf16_t><<<dim3((M_ + 3) / 4), blk, 0, stream>>>(src, attn_out, (const float*)nullptr, g1, beta1, xbuf, M_);

  if (bigws) {
    gemm_bt<MODE_BF16_RELU, false><<<dim3(gM, DFF_ / BN), blk, 0, stream>>>(
        xbuf, 256, wT1, 256, bl1, hiddenF, DFF_, M_, DFF_, 256);
    gemm_bt<MODE_F32, false><<<dim3(gM, 2), blk, 0, stream>>>(
        hiddenF, DFF_, wT2, DFF_, (const float*)nullptr, outf, 256, M_, 256, DFF_);
  } else {
    const int gMC = (MC_ + BM - 1) / BM;   // 105
    for (int c = 0; c < 4; ++c) {
      gemm_bt<MODE_BF16_RELU, false><<<dim3(gMC, DFF_ / BN), blk, 0, stream>>>(
          xbuf + (size_t)c * MC_ * 256, 256, wT1, 256, bl1, hiddenC, DFF_, MC_, DFF_, 256);
      gemm_bt<MODE_F32, false><<<dim3(gMC, 2), blk, 0, stream>>>(
          hiddenC, DFF_, wT2, DFF_, (const float*)nullptr, outf + (size_t)c * MC_ * 256, 256, MC_, 256, DFF_);
    }
  }
  // final LN in-place on d_out (per-thread read-before-write)
  k_ln4<bf16_t, float, float><<<dim3((M_ + 3) / 4), blk, 0, stream>>>(xbuf, outf, bl2, g2, beta2, outf, M_);
}

// Round 4
// 944.993 us; speedup vs baseline: 1.1702x; 1.1702x over previous
//
#include <hip/hip_runtime.h>
#include <hip/hip_bf16.h>

typedef __bf16 bf16_t;
typedef __bf16 bf16x8 __attribute__((ext_vector_type(8)));
typedef float f32x4 __attribute__((ext_vector_type(4)));

#define B_    4
#define LQ_   13343
#define D_    256
#define H_    8
#define HD_   32
#define DFF_  2048
#define M_    (B_ * LQ_)   // 53372 tokens = 4 * 13343 exactly
#define MC_   13343        // M-chunk for FFN (hidden chunk fits Areg+Creg)

// bijective XCD-chunk swizzle (m204): contiguous wgid ranges per XCD
__device__ __forceinline__ int xcd_swz(int orig, int nwg) {
  int q = nwg >> 3, r = nwg & 7;
  int xcd = orig & 7, idx = orig >> 3;
  return (xcd < r ? xcd * (q + 1) : r * (q + 1) + (xcd - r) * q) + idx;
}

// ---------------- GEMM: C = A[M,K] @ Bt[N,K]^T + bias ----------------
#define BM 128
#define BN 128
#define BK 32
// LDS layout LINEAR [128][32] (64 B rows) — required by global_load_lds.

#define MODE_F32       0
#define MODE_F32_ACC   1
#define MODE_BF16      2
#define MODE_BF16_RELU 3

__device__ __forceinline__ void gload_lds16(const void* g, void* l) {
  __builtin_amdgcn_global_load_lds(
      (const __attribute__((address_space(1))) void*)g,
      (__attribute__((address_space(3))) void*)l, 16, 0, 0);
}

// 1D grid = gM * nyb, XCD-chunked swizzle, n-fastest: ny-siblings (sharing an
// A-panel) are adjacent in one XCD chunk; each XCD covers a contiguous m-range.
template <int MODE, bool AF32>
__global__ __launch_bounds__(256) void gemm_bt(
    const void* __restrict__ Av, int lda,
    const bf16_t* __restrict__ Bt, int ldb,
    const float* __restrict__ bias,
    void* __restrict__ Cv, int ldc,
    int M, int N, int K)
{
  __shared__ alignas(16) bf16_t As[BM * BK];   // 8 KB linear [128][32]
  __shared__ alignas(16) bf16_t Bs[BN * BK];   // 8 KB
  const int tid  = threadIdx.x;
  const int wave = tid >> 6, lane = tid & 63;
  const int nyb = (N + BN - 1) / BN;
  const int gid = xcd_swz(blockIdx.x, (int)gridDim.x);
  const int m0 = (gid / nyb) * BM;
  const int n0 = (gid - (gid / nyb) * nyb) * BN;
  const int wm = (wave & 1) * 64;
  const int wn = (wave >> 1) * 64;
  const int lrow = lane & 15;
  const int quad = lane >> 4;

  f32x4 acc[4][4] = {};

  const int srow = wave * 16 + (lane >> 2);
  const int scol = (lane & 3) * 8;
  const bf16_t* Ab = (const bf16_t*)Av;

  const int ar0 = min(m0 + srow,      M - 1);
  const int ar1 = min(m0 + srow + 64, M - 1);
  const int br0 = min(n0 + srow,      N - 1);
  const int br1 = min(n0 + srow + 64, N - 1);

  const int r0 = tid >> 2;          // reg-staging geometry (AF32 path)
  const int kc = (tid & 3) * 8;     // ds_write byte = tid*16, conflict-free

  for (int kt = 0; kt < K; kt += BK) {
    bf16x8 a0 = {}, a1 = {};
    if (AF32) {
      const float* Af = (const float*)Av;
      int gm0 = m0 + r0, gm1 = m0 + r0 + 64;
      if (gm0 < M) {
        const f32x4* p = (const f32x4*)(Af + (size_t)gm0 * lda + kt + kc);
        f32x4 u = p[0], w = p[1];
#pragma unroll
        for (int j = 0; j < 4; ++j) { a0[j] = (bf16_t)u[j]; a0[j + 4] = (bf16_t)w[j]; }
      }
      if (gm1 < M) {
        const f32x4* p = (const f32x4*)(Af + (size_t)gm1 * lda + kt + kc);
        f32x4 u = p[0], w = p[1];
#pragma unroll
        for (int j = 0; j < 4; ++j) { a1[j] = (bf16_t)u[j]; a1[j + 4] = (bf16_t)w[j]; }
      }
    }
    __syncthreads();
    if (AF32) {
      *(bf16x8*)(&As[r0 * BK + kc])        = a0;
      *(bf16x8*)(&As[(r0 + 64) * BK + kc]) = a1;
    } else {
      gload_lds16(Ab + (size_t)ar0 * lda + kt + scol, &As[wave * 512]);
      gload_lds16(Ab + (size_t)ar1 * lda + kt + scol, &As[2048 + wave * 512]);
    }
    gload_lds16(Bt + (size_t)br0 * ldb + kt + scol, &Bs[wave * 512]);
    gload_lds16(Bt + (size_t)br1 * ldb + kt + scol, &Bs[2048 + wave * 512]);
    __syncthreads();

    bf16x8 af[4], bfr[4];
#pragma unroll
    for (int i = 0; i < 4; ++i)
      af[i] = *(const bf16x8*)(&As[(wm + i * 16 + lrow) * BK + quad * 8]);
#pragma unroll
    for (int j = 0; j < 4; ++j)
      bfr[j] = *(const bf16x8*)(&Bs[(wn + j * 16 + lrow) * BK + quad * 8]);
#pragma unroll
    for (int i = 0; i < 4; ++i)
#pragma unroll
      for (int j = 0; j < 4; ++j)
        acc[i][j] = __builtin_amdgcn_mfma_f32_16x16x32_bf16(af[i], bfr[j], acc[i][j], 0, 0, 0);
  }

  float*  Cf = (float*)Cv;
  bf16_t* Cb = (bf16_t*)Cv;
#pragma unroll
  for (int i = 0; i < 4; ++i) {
#pragma unroll
    for (int j = 0; j < 4; ++j) {
      int gn = n0 + wn + j * 16 + lrow;
      if (gn >= N) continue;
      float bv = bias ? bias[gn] : 0.f;
#pragma unroll
      for (int r = 0; r < 4; ++r) {
        int gm = m0 + wm + i * 16 + quad * 4 + r;
        if (gm >= M) continue;
        float v = acc[i][j][r] + bv;
        size_t ci = (size_t)gm * ldc + gn;
        if (MODE == MODE_F32)          Cf[ci] = v;
        else if (MODE == MODE_F32_ACC) Cf[ci] += v;
        else if (MODE == MODE_BF16)    Cb[ci] = (bf16_t)v;
        else                           Cb[ci] = (bf16_t)(v > 0.f ? v : 0.f);
      }
    }
  }
}

// ---- merged offset+attn GEMM: A = (src+pos) inline; N=480 split epilogue ----
// cols 0..319 -> offb bf16 [M,320]; cols 320..479 -> attnb f32 raw logits [M,160]
__global__ __launch_bounds__(256) void gemm_qkv(
    const float* __restrict__ src, const float* __restrict__ pos,
    const bf16_t* __restrict__ Bt,     // wTqkv [480][256]
    const float* __restrict__ b_off, const float* __restrict__ b_attn,
    bf16_t* __restrict__ offb, float* __restrict__ attnb)
{
  __shared__ alignas(16) bf16_t As[BM * BK];
  __shared__ alignas(16) bf16_t Bs[BN * BK];
  const int tid  = threadIdx.x;
  const int wave = tid >> 6, lane = tid & 63;
  const int gid = xcd_swz(blockIdx.x, (int)gridDim.x);
  const int m0 = (gid >> 2) * BM;
  const int n0 = (gid & 3) * BN;
  const int wm = (wave & 1) * 64;
  const int wn = (wave >> 1) * 64;
  const int lrow = lane & 15;
  const int quad = lane >> 4;
  const int N = 480;

  f32x4 acc[4][4] = {};

  const int srow = wave * 16 + (lane >> 2);
  const int scol = (lane & 3) * 8;
  const int br0 = min(n0 + srow,      N - 1);
  const int br1 = min(n0 + srow + 64, N - 1);
  const int r0 = tid >> 2;
  const int kc = (tid & 3) * 8;

  for (int kt = 0; kt < 256; kt += BK) {
    bf16x8 a0 = {}, a1 = {};
    int gm0 = m0 + r0, gm1 = m0 + r0 + 64;
    if (gm0 < M_) {
      const f32x4* ps = (const f32x4*)(src + (size_t)gm0 * 256 + kt + kc);
      const f32x4* pp = (const f32x4*)(pos + (size_t)gm0 * 256 + kt + kc);
      f32x4 u = ps[0] + pp[0], w = ps[1] + pp[1];
#pragma unroll
      for (int j = 0; j < 4; ++j) { a0[j] = (bf16_t)u[j]; a0[j + 4] = (bf16_t)w[j]; }
    }
    if (gm1 < M_) {
      const f32x4* ps = (const f32x4*)(src + (size_t)gm1 * 256 + kt + kc);
      const f32x4* pp = (const f32x4*)(pos + (size_t)gm1 * 256 + kt + kc);
      f32x4 u = ps[0] + pp[0], w = ps[1] + pp[1];
#pragma unroll
      for (int j = 0; j < 4; ++j) { a1[j] = (bf16_t)u[j]; a1[j + 4] = (bf16_t)w[j]; }
    }
    __syncthreads();
    *(bf16x8*)(&As[r0 * BK + kc])        = a0;
    *(bf16x8*)(&As[(r0 + 64) * BK + kc]) = a1;
    gload_lds16(Bt + (size_t)br0 * 256 + kt + scol, &Bs[wave * 512]);
    gload_lds16(Bt + (size_t)br1 * 256 + kt + scol, &Bs[2048 + wave * 512]);
    __syncthreads();

    bf16x8 af[4], bfr[4];
#pragma unroll
    for (int i = 0; i < 4; ++i)
      af[i] = *(const bf16x8*)(&As[(wm + i * 16 + lrow) * BK + quad * 8]);
#pragma unroll
    for (int j = 0; j < 4; ++j)
      bfr[j] = *(const bf16x8*)(&Bs[(wn + j * 16 + lrow) * BK + quad * 8]);
#pragma unroll
    for (int i = 0; i < 4; ++i)
#pragma unroll
      for (int j = 0; j < 4; ++j)
        acc[i][j] = __builtin_amdgcn_mfma_f32_16x16x32_bf16(af[i], bfr[j], acc[i][j], 0, 0, 0);
  }

#pragma unroll
  for (int i = 0; i < 4; ++i) {
#pragma unroll
    for (int j = 0; j < 4; ++j) {
      int gn = n0 + wn + j * 16 + lrow;
      if (gn >= N) continue;
      float bv = (gn < 320) ? b_off[gn] : b_attn[gn - 320];
#pragma unroll
      for (int r = 0; r < 4; ++r) {
        int gm = m0 + wm + i * 16 + quad * 4 + r;
        if (gm >= M_) continue;
        float v = acc[i][j][r] + bv;
        if (gn < 320) offb[(size_t)gm * 320 + gn] = (bf16_t)v;
        else          attnb[(size_t)gm * 160 + gn - 320] = v;
      }
    }
  }
}

// ---------------- small kernels ----------------
// one-launch merged coalesced transpose for all 6 weights
__global__ __launch_bounds__(256) void k_transpose_all(
    const float* __restrict__ i0, const float* __restrict__ i1,
    const float* __restrict__ i2, const float* __restrict__ i3,
    const float* __restrict__ i4, const float* __restrict__ i5,
    bf16_t* __restrict__ o0, bf16_t* __restrict__ o1, bf16_t* __restrict__ o2,
    bf16_t* __restrict__ o3, bf16_t* __restrict__ o4, bf16_t* __restrict__ o5)
{
  int bid = blockIdx.x;
  const float* in; bf16_t* out; int K, N, txn;
  if (bid < 80)        { in = i0; out = o0; K = 256;  N = 320;  txn = 10; }
  else if (bid < 120)  { in = i1; out = o1; K = 256;  N = 160;  bid -= 80;  txn = 5; }
  else if (bid < 184)  { in = i2; out = o2; K = 256;  N = 256;  bid -= 120; txn = 8; }
  else if (bid < 248)  { in = i3; out = o3; K = 256;  N = 256;  bid -= 184; txn = 8; }
  else if (bid < 760)  { in = i4; out = o4; K = 256;  N = 2048; bid -= 248; txn = 64; }
  else                 { in = i5; out = o5; K = 2048; N = 256;  bid -= 760; txn = 8; }
  const int bx = bid % txn, by = bid / txn;
  __shared__ float tile[32][33];
  const int k0 = by * 32, n0 = bx * 32;
  const int tx = threadIdx.x & 31, ty = threadIdx.x >> 5;
#pragma unroll
  for (int r = ty; r < 32; r += 8)
    tile[r][tx] = in[(size_t)(k0 + r) * N + n0 + tx];
  __syncthreads();
#pragma unroll
  for (int r = ty; r < 32; r += 8)
    out[(size_t)(n0 + r) * K + k0 + tx] = (bf16_t)tile[tx][r];
}

// 8 queries/block; 32 threads/query (R2-proven layout: 4 lanes share each
// (q,h) tap -> coalesced 64B value reads, 36 VGPR, ~70% occupancy).
// Softmax over the 20 (l,p) logits fused in-LDS (bit-identical op order).
// XCD-chunked block swizzle: contiguous query ranges per XCD -> value L2 reuse.
__global__ __launch_bounds__(256) void k_sample(
    const bf16_t* __restrict__ value,   // [B*LQ, 256]
    const bf16_t* __restrict__ off,     // [M, 320]
    const float* __restrict__ attn,     // [M, 160] RAW logits
    const float* __restrict__ rp,       // [M, 10]
    bf16_t* __restrict__ core)          // [M, 256]
{
  const int Wl[5] = {100, 50, 25, 13, 7};
  const int st[5] = {0, 10000, 12500, 13125, 13294};
  __shared__ alignas(16) bf16_t s_off[8][320];
  __shared__ alignas(16) float  s_attn[8][160];
  __shared__ float s_rp[8][10];
  const int t = threadIdx.x;
  const int bq0 = xcd_swz(blockIdx.x, (int)gridDim.x) * 8;
  for (int i = t; i < 320; i += 256) {
    int q = i / 40, e = i - q * 40;
    if (bq0 + q < M_) {
      *(bf16x8*)&s_off[q][e * 8] = *(const bf16x8*)(off + (size_t)(bq0 + q) * 320 + e * 8);
      *(f32x4*)&s_attn[q][e * 4] = *(const f32x4*)(attn + (size_t)(bq0 + q) * 160 + e * 4);
    }
  }
  if (t < 80) {
    int q = t / 10, e = t - q * 10;
    if (bq0 + q < M_) s_rp[q][e] = rp[(size_t)(bq0 + q) * 10 + e];
  }
  __syncthreads();
  // fused softmax: thread t<64 owns one (q,h) row of 20 (same serial order as
  // the standalone kernel -> bit-identical). Dead rows produce NaN, unused.
  if (t < 64) {
    float* p = &s_attn[t >> 3][(t & 7) * 20];
    float mx = p[0];
#pragma unroll
    for (int i = 1; i < 20; ++i) mx = fmaxf(mx, p[i]);
    float e[20], sum = 0.f;
#pragma unroll
    for (int i = 0; i < 20; ++i) { e[i] = expf(p[i] - mx); sum += e[i]; }
    float inv = 1.f / sum;
#pragma unroll
    for (int i = 0; i < 20; ++i) p[i] = e[i] * inv;
  }
  __syncthreads();

  const int wq = t >> 5, s = t & 31;
  const int h = s >> 2, d0 = (s & 3) * 8;
  const int bq = bq0 + wq;
  if (bq >= M_) return;
  const int b = bq / LQ_;
  const bf16_t* vbase = value + ((size_t)b * LQ_) * 256 + h * 32 + d0;
  float acc[8] = {};
#pragma unroll
  for (int lvl = 0; lvl < 5; ++lvl) {
    const float W = (float)Wl[lvl];
    const float rx = s_rp[wq][lvl * 2], ry = s_rp[wq][lvl * 2 + 1];
#pragma unroll
    for (int p = 0; p < 4; ++p) {
      const int base = (h * 5 + lvl) * 4 + p;
      float px = rx * W + (float)s_off[wq][base * 2]     - 0.5f;
      float py = ry * W + (float)s_off[wq][base * 2 + 1] - 0.5f;
      float aw = s_attn[wq][h * 20 + lvl * 4 + p];
      float x0f = floorf(px), y0f = floorf(py);
      float wx1 = px - x0f, wy1 = py - y0f;
      int x0 = (int)x0f, y0 = (int)y0f;
#pragma unroll
      for (int dy = 0; dy < 2; ++dy) {
        int yi = y0 + dy;
        bool vy = (yi >= 0) & (yi < Wl[lvl]);
        int yc = min(max(yi, 0), Wl[lvl] - 1);
        float wy = dy ? wy1 : 1.f - wy1;
#pragma unroll
        for (int dx = 0; dx < 2; ++dx) {
          int xi = x0 + dx;
          bool vx = (xi >= 0) & (xi < Wl[lvl]);
          int xc = min(max(xi, 0), Wl[lvl] - 1);
          float cw = (vx & vy) ? aw * wy * (dx ? wx1 : 1.f - wx1) : 0.f;
          bf16x8 v = *(const bf16x8*)(vbase + (size_t)(st[lvl] + yc * Wl[lvl] + xc) * 256);
#pragma unroll
          for (int j = 0; j < 8; ++j) acc[j] += cw * (float)v[j];
        }
      }
    }
  }
  bf16x8 o;
#pragma unroll
  for (int j = 0; j < 8; ++j) o[j] = (bf16_t)acc[j];
  *(bf16x8*)(core + (size_t)bq * 256 + h * 32 + d0) = o;
}

// out = LN(a + res [+ eb]) * g + beta ; one row per wave, 4 rows/block
template <typename TA, typename TR, typename TO>
__global__ __launch_bounds__(256) void k_ln4(
    const TA* __restrict__ a, const TR* __restrict__ res,
    const float* __restrict__ eb, const float* __restrict__ g,
    const float* __restrict__ beta, TO* __restrict__ out, int rows)
{
  const int wave = threadIdx.x >> 6, lane = threadIdx.x & 63;
  const int row = blockIdx.x * 4 + wave;
  if (row >= rows) return;
  const size_t base = (size_t)row * 256 + lane * 4;
  float v[4];
#pragma unroll
  for (int j = 0; j < 4; ++j) {
    v[j] = (float)a[base + j] + (float)res[base + j];
    if (eb) v[j] += eb[lane * 4 + j];
  }
  float s1 = v[0] + v[1] + v[2] + v[3];
  float s2 = v[0] * v[0] + v[1] * v[1] + v[2] * v[2] + v[3] * v[3];
#pragma unroll
  for (int o = 32; o > 0; o >>= 1) { s1 += __shfl_xor(s1, o); s2 += __shfl_xor(s2, o); }
  float m = s1 * (1.f / 256.f);
  float var = s2 * (1.f / 256.f) - m * m;
  float inv = rsqrtf(var + 1e-5f);
#pragma unroll
  for (int j = 0; j < 4; ++j)
    out[base + j] = (TO)(((v[j] - m) * inv) * g[lane * 4 + j] + beta[lane * 4 + j]);
}

// ---------------- launcher ----------------
extern "C" void kernel_launch(void* const* d_in, const int* in_sizes, int n_in,
                              void* d_out, int out_size, void* d_ws, size_t ws_size,
                              hipStream_t stream) {
  const float* src   = (const float*)d_in[0];
  const float* pos   = (const float*)d_in[1];
  const float* rp    = (const float*)d_in[2];
  const float* W_off = (const float*)d_in[5];
  const float* b_off = (const float*)d_in[6];
  const float* W_attn= (const float*)d_in[7];
  const float* b_attn= (const float*)d_in[8];
  const float* W_val = (const float*)d_in[9];
  const float* b_val = (const float*)d_in[10];
  const float* W_out = (const float*)d_in[11];
  const float* b_out = (const float*)d_in[12];
  const float* g1    = (const float*)d_in[13];
  const float* beta1 = (const float*)d_in[14];
  const float* W1    = (const float*)d_in[15];
  const float* bl1   = (const float*)d_in[16];
  const float* W2    = (const float*)d_in[17];
  const float* bl2   = (const float*)d_in[18];
  const float* g2    = (const float*)d_in[19];
  const float* beta2 = (const float*)d_in[20];

  char* ws = (char*)d_ws;
  const size_t SZ_TOK = (size_t)M_ * 256 * 2;  // 27,326,464
  const size_t SZ_ATT = (size_t)M_ * 160 * 4;  // 34,158,080

  size_t o = 0;
  bf16_t* wTqkv = (bf16_t*)(ws + o); o += 480 * 256 * 2;   // off rows 0..319, attn 320..479
  bf16_t* wTval = (bf16_t*)(ws + o); o += 256 * 256 * 2;
  bf16_t* wTout = (bf16_t*)(ws + o); o += 256 * 256 * 2;
  bf16_t* wT1   = (bf16_t*)(ws + o); o += 2048 * 256 * 2;
  bf16_t* wT2   = (bf16_t*)(ws + o); o += 2048 * 256 * 2;
  o = (o + 255) & ~(size_t)255;
  char* Areg = ws + o; o += SZ_TOK;   // coreb; FFN: hidden chunk starts here
  char* Creg = ws + o; o += SZ_ATT;   // attnb -> attn_out (contiguous after Areg)
  char* Dreg = ws + o; o += SZ_TOK;   // valb -> xbuf
  size_t base = o;                    // ~91.4MB

  const bool bigws = (ws_size >= base + (size_t)M_ * 2048 * 2);
  bf16_t* hiddenF = (bf16_t*)(ws + base);   // full [M,2048] (big tier only)
  bf16_t* hiddenC = (bf16_t*)Areg;          // chunk [MC_,2048] = 54.65MB <= 61.5MB

  bf16_t* coreb   = (bf16_t*)Areg;
  float*  attnb   = (float*) Creg;
  bf16_t* attn_out= (bf16_t*)Creg;
  bf16_t* valb    = (bf16_t*)Dreg;
  bf16_t* xbuf    = (bf16_t*)Dreg;
  bf16_t* offb    = (bf16_t*)d_out;   // dead before FFN writes outf
  float*  outf    = (float*) d_out;

  k_transpose_all<<<dim3(1272), 256, 0, stream>>>(
      W_off, W_attn, W_val, W_out, W1, W2,
      wTqkv, wTqkv + 320 * 256, wTval, wTout, wT1, wT2);

  dim3 blk(256);
  const int gM = (M_ + BM - 1) / BM;   // 417

  gemm_qkv<<<dim3(gM * 4), blk, 0, stream>>>(src, pos, wTqkv, b_off, b_attn, offb, attnb);
  gemm_bt<MODE_BF16, true><<<dim3(gM * 2), blk, 0, stream>>>(src, 256, wTval, 256, b_val, valb, 256, M_, 256, 256);
  k_sample<<<dim3((M_ + 7) / 8), blk, 0, stream>>>(valb, offb, attnb, rp, coreb);
  gemm_bt<MODE_BF16, false><<<dim3(gM * 2), blk, 0, stream>>>(coreb, 256, wTout, 256, b_out, attn_out, 256, M_, 256, 256);
  k_ln4<float, bf16_t, bf16_t><<<dim3((M_ + 3) / 4), blk, 0, stream>>>(src, attn_out, (const float*)nullptr, g1, beta1, xbuf, M_);

  if (bigws) {
    gemm_bt<MODE_BF16_RELU, false><<<dim3(gM * (DFF_ / BN)), blk, 0, stream>>>(
        xbuf, 256, wT1, 256, bl1, hiddenF, DFF_, M_, DFF_, 256);
    gemm_bt<MODE_F32, false><<<dim3(gM * 2), blk, 0, stream>>>(
        hiddenF, DFF_, wT2, DFF_, (const float*)nullptr, outf, 256, M_, 256, DFF_);
  } else {
    const int gMC = (MC_ + BM - 1) / BM;   // 105
    for (int c = 0; c < 4; ++c) {
      gemm_bt<MODE_BF16_RELU, false><<<dim3(gMC * (DFF_ / BN)), blk, 0, stream>>>(
          xbuf + (size_t)c * MC_ * 256, 256, wT1, 256, bl1, hiddenC, DFF_, MC_, DFF_, 256);
      gemm_bt<MODE_F32, false><<<dim3(gMC * 2), blk, 0, stream>>>(
          hiddenC, DFF_, wT2, DFF_, (const float*)nullptr, outf + (size_t)c * MC_ * 256, 256, MC_, 256, DFF_);
    }
  }
  // final LN in-place on d_out (per-thread read-before-write)
  k_ln4<bf16_t, float, float><<<dim3((M_ + 3) / 4), blk, 0, stream>>>(xbuf, outf, bl2, g2, beta2, outf, M_);
}

// Round 5
// 725.146 us; speedup vs baseline: 1.5250x; 1.3032x over previous
//
#include <hip/hip_runtime.h>
#include <hip/hip_bf16.h>

typedef __bf16 bf16_t;
typedef __bf16 bf16x8 __attribute__((ext_vector_type(8)));
typedef float f32x4 __attribute__((ext_vector_type(4)));

#define B_    4
#define LQ_   13343
#define D_    256
#define H_    8
#define HD_   32
#define DFF_  2048
#define M_    (B_ * LQ_)   // 53372 tokens

// bijective XCD-chunk swizzle (m204): contiguous wgid ranges per XCD
__device__ __forceinline__ int xcd_swz(int orig, int nwg) {
  int q = nwg >> 3, r = nwg & 7;
  int xcd = orig & 7, idx = orig >> 3;
  return (xcd < r ? xcd * (q + 1) : r * (q + 1) + (xcd - r) * q) + idx;
}

// ---------------- GEMM: C = A[M,K] @ Bt[N,K]^T + bias ----------------
#define BM 128
#define BN 128
#define BK 32
// LDS layout LINEAR [128][32] (64 B rows) — required by global_load_lds.

#define MODE_F32       0
#define MODE_F32_ACC   1
#define MODE_BF16      2
#define MODE_BF16_RELU 3

__device__ __forceinline__ void gload_lds16(const void* g, void* l) {
  __builtin_amdgcn_global_load_lds(
      (const __attribute__((address_space(1))) void*)g,
      (__attribute__((address_space(3))) void*)l, 16, 0, 0);
}

// 1D grid = gM * nyb, XCD-chunked swizzle, n-fastest.
template <int MODE, bool AF32>
__global__ __launch_bounds__(256) void gemm_bt(
    const void* __restrict__ Av, int lda,
    const bf16_t* __restrict__ Bt, int ldb,
    const float* __restrict__ bias,
    void* __restrict__ Cv, int ldc,
    int M, int N, int K)
{
  __shared__ alignas(16) bf16_t As[BM * BK];   // 8 KB linear [128][32]
  __shared__ alignas(16) bf16_t Bs[BN * BK];   // 8 KB
  const int tid  = threadIdx.x;
  const int wave = tid >> 6, lane = tid & 63;
  const int nyb = (N + BN - 1) / BN;
  const int gid = xcd_swz(blockIdx.x, (int)gridDim.x);
  const int m0 = (gid / nyb) * BM;
  const int n0 = (gid - (gid / nyb) * nyb) * BN;
  const int wm = (wave & 1) * 64;
  const int wn = (wave >> 1) * 64;
  const int lrow = lane & 15;
  const int quad = lane >> 4;

  f32x4 acc[4][4] = {};

  const int srow = wave * 16 + (lane >> 2);
  const int scol = (lane & 3) * 8;
  const bf16_t* Ab = (const bf16_t*)Av;

  const int ar0 = min(m0 + srow,      M - 1);
  const int ar1 = min(m0 + srow + 64, M - 1);
  const int br0 = min(n0 + srow,      N - 1);
  const int br1 = min(n0 + srow + 64, N - 1);

  const int r0 = tid >> 2;          // reg-staging geometry (AF32 path)
  const int kc = (tid & 3) * 8;     // ds_write byte = tid*16, conflict-free

  for (int kt = 0; kt < K; kt += BK) {
    bf16x8 a0 = {}, a1 = {};
    if (AF32) {
      const float* Af = (const float*)Av;
      int gm0 = m0 + r0, gm1 = m0 + r0 + 64;
      if (gm0 < M) {
        const f32x4* p = (const f32x4*)(Af + (size_t)gm0 * lda + kt + kc);
        f32x4 u = p[0], w = p[1];
#pragma unroll
        for (int j = 0; j < 4; ++j) { a0[j] = (bf16_t)u[j]; a0[j + 4] = (bf16_t)w[j]; }
      }
      if (gm1 < M) {
        const f32x4* p = (const f32x4*)(Af + (size_t)gm1 * lda + kt + kc);
        f32x4 u = p[0], w = p[1];
#pragma unroll
        for (int j = 0; j < 4; ++j) { a1[j] = (bf16_t)u[j]; a1[j + 4] = (bf16_t)w[j]; }
      }
    }
    __syncthreads();
    if (AF32) {
      *(bf16x8*)(&As[r0 * BK + kc])        = a0;
      *(bf16x8*)(&As[(r0 + 64) * BK + kc]) = a1;
    } else {
      gload_lds16(Ab + (size_t)ar0 * lda + kt + scol, &As[wave * 512]);
      gload_lds16(Ab + (size_t)ar1 * lda + kt + scol, &As[2048 + wave * 512]);
    }
    gload_lds16(Bt + (size_t)br0 * ldb + kt + scol, &Bs[wave * 512]);
    gload_lds16(Bt + (size_t)br1 * ldb + kt + scol, &Bs[2048 + wave * 512]);
    __syncthreads();

    bf16x8 af[4], bfr[4];
#pragma unroll
    for (int i = 0; i < 4; ++i)
      af[i] = *(const bf16x8*)(&As[(wm + i * 16 + lrow) * BK + quad * 8]);
#pragma unroll
    for (int j = 0; j < 4; ++j)
      bfr[j] = *(const bf16x8*)(&Bs[(wn + j * 16 + lrow) * BK + quad * 8]);
#pragma unroll
    for (int i = 0; i < 4; ++i)
#pragma unroll
      for (int j = 0; j < 4; ++j)
        acc[i][j] = __builtin_amdgcn_mfma_f32_16x16x32_bf16(af[i], bfr[j], acc[i][j], 0, 0, 0);
  }

  float*  Cf = (float*)Cv;
  bf16_t* Cb = (bf16_t*)Cv;
#pragma unroll
  for (int i = 0; i < 4; ++i) {
#pragma unroll
    for (int j = 0; j < 4; ++j) {
      int gn = n0 + wn + j * 16 + lrow;
      if (gn >= N) continue;
      float bv = bias ? bias[gn] : 0.f;
#pragma unroll
      for (int r = 0; r < 4; ++r) {
        int gm = m0 + wm + i * 16 + quad * 4 + r;
        if (gm >= M) continue;
        float v = acc[i][j][r] + bv;
        size_t ci = (size_t)gm * ldc + gn;
        if (MODE == MODE_F32)          Cf[ci] = v;
        else if (MODE == MODE_F32_ACC) Cf[ci] += v;
        else if (MODE == MODE_BF16)    Cb[ci] = (bf16_t)v;
        else                           Cb[ci] = (bf16_t)(v > 0.f ? v : 0.f);
      }
    }
  }
}

// ---- merged offset+attn GEMM: A = (src+pos) inline; N=480 split epilogue ----
__global__ __launch_bounds__(256) void gemm_qkv(
    const float* __restrict__ src, const float* __restrict__ pos,
    const bf16_t* __restrict__ Bt,     // wTqkv [480][256]
    const float* __restrict__ b_off, const float* __restrict__ b_attn,
    bf16_t* __restrict__ offb, float* __restrict__ attnb)
{
  __shared__ alignas(16) bf16_t As[BM * BK];
  __shared__ alignas(16) bf16_t Bs[BN * BK];
  const int tid  = threadIdx.x;
  const int wave = tid >> 6, lane = tid & 63;
  const int gid = xcd_swz(blockIdx.x, (int)gridDim.x);
  const int m0 = (gid >> 2) * BM;
  const int n0 = (gid & 3) * BN;
  const int wm = (wave & 1) * 64;
  const int wn = (wave >> 1) * 64;
  const int lrow = lane & 15;
  const int quad = lane >> 4;
  const int N = 480;

  f32x4 acc[4][4] = {};

  const int srow = wave * 16 + (lane >> 2);
  const int scol = (lane & 3) * 8;
  const int br0 = min(n0 + srow,      N - 1);
  const int br1 = min(n0 + srow + 64, N - 1);
  const int r0 = tid >> 2;
  const int kc = (tid & 3) * 8;

  for (int kt = 0; kt < 256; kt += BK) {
    bf16x8 a0 = {}, a1 = {};
    int gm0 = m0 + r0, gm1 = m0 + r0 + 64;
    if (gm0 < M_) {
      const f32x4* ps = (const f32x4*)(src + (size_t)gm0 * 256 + kt + kc);
      const f32x4* pp = (const f32x4*)(pos + (size_t)gm0 * 256 + kt + kc);
      f32x4 u = ps[0] + pp[0], w = ps[1] + pp[1];
#pragma unroll
      for (int j = 0; j < 4; ++j) { a0[j] = (bf16_t)u[j]; a0[j + 4] = (bf16_t)w[j]; }
    }
    if (gm1 < M_) {
      const f32x4* ps = (const f32x4*)(src + (size_t)gm1 * 256 + kt + kc);
      const f32x4* pp = (const f32x4*)(pos + (size_t)gm1 * 256 + kt + kc);
      f32x4 u = ps[0] + pp[0], w = ps[1] + pp[1];
#pragma unroll
      for (int j = 0; j < 4; ++j) { a1[j] = (bf16_t)u[j]; a1[j + 4] = (bf16_t)w[j]; }
    }
    __syncthreads();
    *(bf16x8*)(&As[r0 * BK + kc])        = a0;
    *(bf16x8*)(&As[(r0 + 64) * BK + kc]) = a1;
    gload_lds16(Bt + (size_t)br0 * 256 + kt + scol, &Bs[wave * 512]);
    gload_lds16(Bt + (size_t)br1 * 256 + kt + scol, &Bs[2048 + wave * 512]);
    __syncthreads();

    bf16x8 af[4], bfr[4];
#pragma unroll
    for (int i = 0; i < 4; ++i)
      af[i] = *(const bf16x8*)(&As[(wm + i * 16 + lrow) * BK + quad * 8]);
#pragma unroll
    for (int j = 0; j < 4; ++j)
      bfr[j] = *(const bf16x8*)(&Bs[(wn + j * 16 + lrow) * BK + quad * 8]);
#pragma unroll
    for (int i = 0; i < 4; ++i)
#pragma unroll
      for (int j = 0; j < 4; ++j)
        acc[i][j] = __builtin_amdgcn_mfma_f32_16x16x32_bf16(af[i], bfr[j], acc[i][j], 0, 0, 0);
  }

#pragma unroll
  for (int i = 0; i < 4; ++i) {
#pragma unroll
    for (int j = 0; j < 4; ++j) {
      int gn = n0 + wn + j * 16 + lrow;
      if (gn >= N) continue;
      float bv = (gn < 320) ? b_off[gn] : b_attn[gn - 320];
#pragma unroll
      for (int r = 0; r < 4; ++r) {
        int gm = m0 + wm + i * 16 + quad * 4 + r;
        if (gm >= M_) continue;
        float v = acc[i][j][r] + bv;
        if (gn < 320) offb[(size_t)gm * 320 + gn] = (bf16_t)v;
        else          attnb[(size_t)gm * 160 + gn - 320] = v;
      }
    }
  }
}

// ---------------- fused FFN: outf = relu(x@W1+bl1) @ W2, hidden never hits HBM ----
// block = 64 token-rows; 16 hidden chunks of 128; h kept in LDS (bf16, exact same
// rounding as the old hidden buffer); C acc order = sequential K 0..2047 by 32
// => bit-identical to the unfused path.
__global__ __launch_bounds__(256) void k_ffn(
    const bf16_t* __restrict__ x,     // [M,256] bf16 (xbuf)
    const bf16_t* __restrict__ w1t,   // [2048][256]
    const float* __restrict__ bl1,    // [2048]
    const bf16_t* __restrict__ w2t,   // [256][2048]
    float* __restrict__ outf)         // [M,256] f32
{
  __shared__ alignas(16) bf16_t xs[8][64 * 32];     // 32KB, x k-tiles
  __shared__ alignas(16) bf16_t hs[4][64 * 32];     // 16KB, h k-tiles
  __shared__ alignas(16) bf16_t wstage[256 * 32];   // 16KB (W1 uses first 8KB)
  const int tid  = threadIdx.x;
  const int wave = tid >> 6, lane = tid & 63;
  const int lrow = lane & 15, quad = lane >> 4;
  const int m0 = xcd_swz(blockIdx.x, (int)gridDim.x) * 64;
  const int srow = lane >> 2;            // staging row-within-16
  const int scol = (lane & 3) * 8;       // staging col elems
  const int wc0 = wave * 64;             // wave's C col base

  // stage x once: call c -> k-tile c, wave w rows w*16+(l>>2)
  {
    int gr = min(m0 + wave * 16 + srow, M_ - 1);
#pragma unroll
    for (int c = 0; c < 8; ++c)
      gload_lds16(x + (size_t)gr * 256 + c * 32 + scol, &xs[c][wave * 512]);
  }

  f32x4 cacc[4][4] = {};   // C[64][wc0..wc0+64): i row-tile, j col-tile

  for (int hc = 0; hc < 16; ++hc) {
    f32x4 hacc[4][2] = {};   // h[64][wave*32..+32)
    for (int kt = 0; kt < 8; ++kt) {
      __syncthreads();       // wstage free (prev readers done); 1st iter: x staged
#pragma unroll
      for (int c = 0; c < 2; ++c) {
        int r = c * 64 + wave * 16 + srow;
        gload_lds16(w1t + (size_t)(hc * 128 + r) * 256 + kt * 32 + scol,
                    &wstage[c * 2048 + wave * 512]);
      }
      __syncthreads();       // W1 tile staged
      bf16x8 af[4], bf[2];
#pragma unroll
      for (int i = 0; i < 4; ++i)
        af[i] = *(const bf16x8*)(&xs[kt][(i * 16 + lrow) * 32 + quad * 8]);
#pragma unroll
      for (int j = 0; j < 2; ++j)
        bf[j] = *(const bf16x8*)(&wstage[(wave * 32 + j * 16 + lrow) * 32 + quad * 8]);
#pragma unroll
      for (int i = 0; i < 4; ++i)
#pragma unroll
        for (int j = 0; j < 2; ++j)
          hacc[i][j] = __builtin_amdgcn_mfma_f32_16x16x32_bf16(af[i], bf[j], hacc[i][j], 0, 0, 0);
    }
    // h -> LDS with bias+relu, bf16 (wave owns h cols [wave*32,+32) = k-tile `wave`)
    {
      float b0 = bl1[hc * 128 + wave * 32 + lrow];
      float b1 = bl1[hc * 128 + wave * 32 + 16 + lrow];
#pragma unroll
      for (int i = 0; i < 4; ++i)
#pragma unroll
        for (int j = 0; j < 2; ++j) {
          float bb = j ? b1 : b0;
#pragma unroll
          for (int r = 0; r < 4; ++r) {
            float v = hacc[i][j][r] + bb;
            hs[wave][(i * 16 + quad * 4 + r) * 32 + j * 16 + lrow] =
                (bf16_t)(v > 0.f ? v : 0.f);
          }
        }
    }
    __syncthreads();         // h visible; GEMM1's wstage readers drained
    for (int kt2 = 0; kt2 < 4; ++kt2) {
      if (kt2) __syncthreads();   // wstage free
#pragma unroll
      for (int c = 0; c < 4; ++c) {
        int r = c * 64 + wave * 16 + srow;
        gload_lds16(w2t + (size_t)r * 2048 + hc * 128 + kt2 * 32 + scol,
                    &wstage[c * 2048 + wave * 512]);
      }
      __syncthreads();       // W2 tile staged
      bf16x8 af2[4], bf2[4];
#pragma unroll
      for (int i = 0; i < 4; ++i)
        af2[i] = *(const bf16x8*)(&hs[kt2][(i * 16 + lrow) * 32 + quad * 8]);
#pragma unroll
      for (int j = 0; j < 4; ++j)
        bf2[j] = *(const bf16x8*)(&wstage[(wc0 + j * 16 + lrow) * 32 + quad * 8]);
#pragma unroll
      for (int i = 0; i < 4; ++i)
#pragma unroll
        for (int j = 0; j < 4; ++j)
          cacc[i][j] = __builtin_amdgcn_mfma_f32_16x16x32_bf16(af2[i], bf2[j], cacc[i][j], 0, 0, 0);
    }
  }

#pragma unroll
  for (int i = 0; i < 4; ++i)
#pragma unroll
    for (int j = 0; j < 4; ++j)
#pragma unroll
      for (int r = 0; r < 4; ++r) {
        int gm = m0 + i * 16 + quad * 4 + r;
        if (gm < M_) outf[(size_t)gm * 256 + wc0 + j * 16 + lrow] = cacc[i][j][r];
      }
}

// ---------------- small kernels ----------------
__global__ __launch_bounds__(256) void k_transpose_all(
    const float* __restrict__ i0, const float* __restrict__ i1,
    const float* __restrict__ i2, const float* __restrict__ i3,
    const float* __restrict__ i4, const float* __restrict__ i5,
    bf16_t* __restrict__ o0, bf16_t* __restrict__ o1, bf16_t* __restrict__ o2,
    bf16_t* __restrict__ o3, bf16_t* __restrict__ o4, bf16_t* __restrict__ o5)
{
  int bid = blockIdx.x;
  const float* in; bf16_t* out; int K, N, txn;
  if (bid < 80)        { in = i0; out = o0; K = 256;  N = 320;  txn = 10; }
  else if (bid < 120)  { in = i1; out = o1; K = 256;  N = 160;  bid -= 80;  txn = 5; }
  else if (bid < 184)  { in = i2; out = o2; K = 256;  N = 256;  bid -= 120; txn = 8; }
  else if (bid < 248)  { in = i3; out = o3; K = 256;  N = 256;  bid -= 184; txn = 8; }
  else if (bid < 760)  { in = i4; out = o4; K = 256;  N = 2048; bid -= 248; txn = 64; }
  else                 { in = i5; out = o5; K = 2048; N = 256;  bid -= 760; txn = 8; }
  const int bx = bid % txn, by = bid / txn;
  __shared__ float tile[32][33];
  const int k0 = by * 32, n0 = bx * 32;
  const int tx = threadIdx.x & 31, ty = threadIdx.x >> 5;
#pragma unroll
  for (int r = ty; r < 32; r += 8)
    tile[r][tx] = in[(size_t)(k0 + r) * N + n0 + tx];
  __syncthreads();
#pragma unroll
  for (int r = ty; r < 32; r += 8)
    out[(size_t)(n0 + r) * K + k0 + tx] = (bf16_t)tile[tx][r];
}

// 8 queries/block; 32 threads/query; fused in-LDS softmax; XCD swizzle.
__global__ __launch_bounds__(256) void k_sample(
    const bf16_t* __restrict__ value,   // [B*LQ, 256]
    const bf16_t* __restrict__ off,     // [M, 320]
    const float* __restrict__ attn,     // [M, 160] RAW logits
    const float* __restrict__ rp,       // [M, 10]
    bf16_t* __restrict__ core)          // [M, 256]
{
  const int Wl[5] = {100, 50, 25, 13, 7};
  const int st[5] = {0, 10000, 12500, 13125, 13294};
  __shared__ alignas(16) bf16_t s_off[8][320];
  __shared__ alignas(16) float  s_attn[8][160];
  __shared__ float s_rp[8][10];
  const int t = threadIdx.x;
  const int bq0 = xcd_swz(blockIdx.x, (int)gridDim.x) * 8;
  for (int i = t; i < 320; i += 256) {
    int q = i / 40, e = i - q * 40;
    if (bq0 + q < M_) {
      *(bf16x8*)&s_off[q][e * 8] = *(const bf16x8*)(off + (size_t)(bq0 + q) * 320 + e * 8);
      *(f32x4*)&s_attn[q][e * 4] = *(const f32x4*)(attn + (size_t)(bq0 + q) * 160 + e * 4);
    }
  }
  if (t < 80) {
    int q = t / 10, e = t - q * 10;
    if (bq0 + q < M_) s_rp[q][e] = rp[(size_t)(bq0 + q) * 10 + e];
  }
  __syncthreads();
  if (t < 64) {
    float* p = &s_attn[t >> 3][(t & 7) * 20];
    float mx = p[0];
#pragma unroll
    for (int i = 1; i < 20; ++i) mx = fmaxf(mx, p[i]);
    float e[20], sum = 0.f;
#pragma unroll
    for (int i = 0; i < 20; ++i) { e[i] = expf(p[i] - mx); sum += e[i]; }
    float inv = 1.f / sum;
#pragma unroll
    for (int i = 0; i < 20; ++i) p[i] = e[i] * inv;
  }
  __syncthreads();

  const int wq = t >> 5, s = t & 31;
  const int h = s >> 2, d0 = (s & 3) * 8;
  const int bq = bq0 + wq;
  if (bq >= M_) return;
  const int b = bq / LQ_;
  const bf16_t* vbase = value + ((size_t)b * LQ_) * 256 + h * 32 + d0;
  float acc[8] = {};
#pragma unroll
  for (int lvl = 0; lvl < 5; ++lvl) {
    const float W = (float)Wl[lvl];
    const float rx = s_rp[wq][lvl * 2], ry = s_rp[wq][lvl * 2 + 1];
#pragma unroll
    for (int p = 0; p < 4; ++p) {
      const int base = (h * 5 + lvl) * 4 + p;
      float px = rx * W + (float)s_off[wq][base * 2]     - 0.5f;
      float py = ry * W + (float)s_off[wq][base * 2 + 1] - 0.5f;
      float aw = s_attn[wq][h * 20 + lvl * 4 + p];
      float x0f = floorf(px), y0f = floorf(py);
      float wx1 = px - x0f, wy1 = py - y0f;
      int x0 = (int)x0f, y0 = (int)y0f;
#pragma unroll
      for (int dy = 0; dy < 2; ++dy) {
        int yi = y0 + dy;
        bool vy = (yi >= 0) & (yi < Wl[lvl]);
        int yc = min(max(yi, 0), Wl[lvl] - 1);
        float wy = dy ? wy1 : 1.f - wy1;
#pragma unroll
        for (int dx = 0; dx < 2; ++dx) {
          int xi = x0 + dx;
          bool vx = (xi >= 0) & (xi < Wl[lvl]);
          int xc = min(max(xi, 0), Wl[lvl] - 1);
          float cw = (vx & vy) ? aw * wy * (dx ? wx1 : 1.f - wx1) : 0.f;
          bf16x8 v = *(const bf16x8*)(vbase + (size_t)(st[lvl] + yc * Wl[lvl] + xc) * 256);
#pragma unroll
          for (int j = 0; j < 8; ++j) acc[j] += cw * (float)v[j];
        }
      }
    }
  }
  bf16x8 o;
#pragma unroll
  for (int j = 0; j < 8; ++j) o[j] = (bf16_t)acc[j];
  *(bf16x8*)(core + (size_t)bq * 256 + h * 32 + d0) = o;
}

// out = LN(a + res [+ eb]) * g + beta ; one row per wave
template <typename TA, typename TR, typename TO>
__global__ __launch_bounds__(256) void k_ln4(
    const TA* __restrict__ a, const TR* __restrict__ res,
    const float* __restrict__ eb, const float* __restrict__ g,
    const float* __restrict__ beta, TO* __restrict__ out, int rows)
{
  const int wave = threadIdx.x >> 6, lane = threadIdx.x & 63;
  const int row = blockIdx.x * 4 + wave;
  if (row >= rows) return;
  const size_t base = (size_t)row * 256 + lane * 4;
  float v[4];
#pragma unroll
  for (int j = 0; j < 4; ++j) {
    v[j] = (float)a[base + j] + (float)res[base + j];
    if (eb) v[j] += eb[lane * 4 + j];
  }
  float s1 = v[0] + v[1] + v[2] + v[3];
  float s2 = v[0] * v[0] + v[1] * v[1] + v[2] * v[2] + v[3] * v[3];
#pragma unroll
  for (int o = 32; o > 0; o >>= 1) { s1 += __shfl_xor(s1, o); s2 += __shfl_xor(s2, o); }
  float m = s1 * (1.f / 256.f);
  float var = s2 * (1.f / 256.f) - m * m;
  float inv = rsqrtf(var + 1e-5f);
#pragma unroll
  for (int j = 0; j < 4; ++j)
    out[base + j] = (TO)(((v[j] - m) * inv) * g[lane * 4 + j] + beta[lane * 4 + j]);
}

// ---------------- launcher ----------------
extern "C" void kernel_launch(void* const* d_in, const int* in_sizes, int n_in,
                              void* d_out, int out_size, void* d_ws, size_t ws_size,
                              hipStream_t stream) {
  const float* src   = (const float*)d_in[0];
  const float* pos   = (const float*)d_in[1];
  const float* rp    = (const float*)d_in[2];
  const float* W_off = (const float*)d_in[5];
  const float* b_off = (const float*)d_in[6];
  const float* W_attn= (const float*)d_in[7];
  const float* b_attn= (const float*)d_in[8];
  const float* W_val = (const float*)d_in[9];
  const float* b_val = (const float*)d_in[10];
  const float* W_out = (const float*)d_in[11];
  const float* b_out = (const float*)d_in[12];
  const float* g1    = (const float*)d_in[13];
  const float* beta1 = (const float*)d_in[14];
  const float* W1    = (const float*)d_in[15];
  const float* bl1   = (const float*)d_in[16];
  const float* W2    = (const float*)d_in[17];
  const float* bl2   = (const float*)d_in[18];
  const float* g2    = (const float*)d_in[19];
  const float* beta2 = (const float*)d_in[20];

  char* ws = (char*)d_ws;
  const size_t SZ_TOK = (size_t)M_ * 256 * 2;  // 27,326,464
  const size_t SZ_ATT = (size_t)M_ * 160 * 4;  // 34,158,080

  size_t o = 0;
  bf16_t* wTqkv = (bf16_t*)(ws + o); o += 480 * 256 * 2;
  bf16_t* wTval = (bf16_t*)(ws + o); o += 256 * 256 * 2;
  bf16_t* wTout = (bf16_t*)(ws + o); o += 256 * 256 * 2;
  bf16_t* wT1   = (bf16_t*)(ws + o); o += 2048 * 256 * 2;
  bf16_t* wT2   = (bf16_t*)(ws + o); o += 2048 * 256 * 2;
  o = (o + 255) & ~(size_t)255;
  char* Areg = ws + o; o += SZ_TOK;   // coreb
  char* Creg = ws + o; o += SZ_ATT;   // attnb -> attn_out
  char* Dreg = ws + o; o += SZ_TOK;   // valb -> xbuf

  bf16_t* coreb   = (bf16_t*)Areg;
  float*  attnb   = (float*) Creg;
  bf16_t* attn_out= (bf16_t*)Creg;
  bf16_t* valb    = (bf16_t*)Dreg;
  bf16_t* xbuf    = (bf16_t*)Dreg;
  bf16_t* offb    = (bf16_t*)d_out;   // dead before k_ffn writes outf
  float*  outf    = (float*) d_out;

  k_transpose_all<<<dim3(1272), 256, 0, stream>>>(
      W_off, W_attn, W_val, W_out, W1, W2,
      wTqkv, wTqkv + 320 * 256, wTval, wTout, wT1, wT2);

  dim3 blk(256);
  const int gM = (M_ + BM - 1) / BM;   // 417

  gemm_qkv<<<dim3(gM * 4), blk, 0, stream>>>(src, pos, wTqkv, b_off, b_attn, offb, attnb);
  gemm_bt<MODE_BF16, true><<<dim3(gM * 2), blk, 0, stream>>>(src, 256, wTval, 256, b_val, valb, 256, M_, 256, 256);
  k_sample<<<dim3((M_ + 7) / 8), blk, 0, stream>>>(valb, offb, attnb, rp, coreb);
  gemm_bt<MODE_BF16, false><<<dim3(gM * 2), blk, 0, stream>>>(coreb, 256, wTout, 256, b_out, attn_out, 256, M_, 256, 256);
  k_ln4<float, bf16_t, bf16_t><<<dim3((M_ + 3) / 4), blk, 0, stream>>>(src, attn_out, (const float*)nullptr, g1, beta1, xbuf, M_);

  // fused FFN: no hidden buffer, no workspace tier
  k_ffn<<<dim3((M_ + 63) / 64), blk, 0, stream>>>(xbuf, wT1, bl1, wT2, outf);

  k_ln4<bf16_t, float, float><<<dim3((M_ + 3) / 4), blk, 0, stream>>>(xbuf, outf, bl2, g2, beta2, outf, M_);
}

// Round 6
// 711.386 us; speedup vs baseline: 1.5545x; 1.0193x over previous
//
#include <hip/hip_runtime.h>
#include <hip/hip_bf16.h>

typedef __bf16 bf16_t;
typedef __bf16 bf16x8 __attribute__((ext_vector_type(8)));
typedef float f32x4 __attribute__((ext_vector_type(4)));

#define B_    4
#define LQ_   13343
#define D_    256
#define H_    8
#define HD_   32
#define DFF_  2048
#define M_    (B_ * LQ_)   // 53372 tokens

// bijective XCD-chunk swizzle (m204): contiguous wgid ranges per XCD
__device__ __forceinline__ int xcd_swz(int orig, int nwg) {
  int q = nwg >> 3, r = nwg & 7;
  int xcd = orig & 7, idx = orig >> 3;
  return (xcd < r ? xcd * (q + 1) : r * (q + 1) + (xcd - r) * q) + idx;
}

#define BM 128
#define BN 128
#define BK 32

#define MODE_F32       0
#define MODE_BF16      2
#define MODE_BF16_RELU 3

__device__ __forceinline__ void gload_lds16(const void* g, void* l) {
  __builtin_amdgcn_global_load_lds(
      (const __attribute__((address_space(1))) void*)g,
      (__attribute__((address_space(3))) void*)l, 16, 0, 0);
}

// ---------------- GEMM: C = A[M,K] @ Bt[N,K]^T + bias ----------------
// 2-phase pipeline: stage(kt+1) issued BEFORE compute(kt); single barrier/step
// (the __syncthreads vmcnt(0) drain overlaps the MFMA phase). Double-buffered LDS.
template <int MODE, bool AF32>
__global__ __launch_bounds__(256) void gemm_bt(
    const void* __restrict__ Av, int lda,
    const bf16_t* __restrict__ Bt, int ldb,
    const float* __restrict__ bias,
    void* __restrict__ Cv, int ldc,
    int M, int N, int K)
{
  __shared__ alignas(16) bf16_t As[2][BM * BK];   // 2 x 8 KB
  __shared__ alignas(16) bf16_t Bs[2][BN * BK];
  const int tid  = threadIdx.x;
  const int wave = tid >> 6, lane = tid & 63;
  const int nyb = (N + BN - 1) / BN;
  const int gid = xcd_swz(blockIdx.x, (int)gridDim.x);
  const int m0 = (gid / nyb) * BM;
  const int n0 = (gid - (gid / nyb) * nyb) * BN;
  const int wm = (wave & 1) * 64;
  const int wn = (wave >> 1) * 64;
  const int lrow = lane & 15;
  const int quad = lane >> 4;

  const int srow = wave * 16 + (lane >> 2);
  const int scol = (lane & 3) * 8;
  const bf16_t* Ab = (const bf16_t*)Av;
  const float*  Af = (const float*)Av;

  const int ar0 = min(m0 + srow,      M - 1);
  const int ar1 = min(m0 + srow + 64, M - 1);
  const int br0 = min(n0 + srow,      N - 1);
  const int br1 = min(n0 + srow + 64, N - 1);

  const int r0 = tid >> 2;            // AF32 reg-staging geometry
  const int kc = (tid & 3) * 8;       // ds_write byte = tid*16, conflict-free
  const int arw0 = min(m0 + r0,      M - 1);
  const int arw1 = min(m0 + r0 + 64, M - 1);

  auto stage_async = [&](int ke, int buf) {  // B always; A via gload when !AF32
    if (!AF32) {
      gload_lds16(Ab + (size_t)ar0 * lda + ke + scol, &As[buf][wave * 512]);
      gload_lds16(Ab + (size_t)ar1 * lda + ke + scol, &As[buf][2048 + wave * 512]);
    }
    gload_lds16(Bt + (size_t)br0 * ldb + ke + scol, &Bs[buf][wave * 512]);
    gload_lds16(Bt + (size_t)br1 * ldb + ke + scol, &Bs[buf][2048 + wave * 512]);
  };

  // prologue: stage kt=0 into buf 0
  if (AF32) {
    const f32x4* p0 = (const f32x4*)(Af + (size_t)arw0 * lda + kc);
    const f32x4* p1 = (const f32x4*)(Af + (size_t)arw1 * lda + kc);
    f32x4 u0 = p0[0], w0 = p0[1], u1 = p1[0], w1 = p1[1];
    bf16x8 a0, a1;
#pragma unroll
    for (int j = 0; j < 4; ++j) {
      a0[j] = (bf16_t)u0[j]; a0[j + 4] = (bf16_t)w0[j];
      a1[j] = (bf16_t)u1[j]; a1[j + 4] = (bf16_t)w1[j];
    }
    *(bf16x8*)(&As[0][r0 * BK + kc])        = a0;
    *(bf16x8*)(&As[0][(r0 + 64) * BK + kc]) = a1;
  }
  stage_async(0, 0);
  __syncthreads();

  f32x4 acc[4][4] = {};
  const int nkt = K / BK;
  for (int kt = 0; kt < nkt; ++kt) {
    const int cur = kt & 1, nxt = cur ^ 1;
    const bool more = (kt + 1) < nkt;
    f32x4 u0 = {}, w0 = {}, u1 = {}, w1 = {};
    if (more) {
      const int ke = (kt + 1) * BK;
      if (AF32) {           // issue f32 loads now; convert+write after compute
        const f32x4* p0 = (const f32x4*)(Af + (size_t)arw0 * lda + ke + kc);
        const f32x4* p1 = (const f32x4*)(Af + (size_t)arw1 * lda + ke + kc);
        u0 = p0[0]; w0 = p0[1]; u1 = p1[0]; w1 = p1[1];
      }
      stage_async(ke, nxt);
    }
    bf16x8 af[4], bfr[4];
#pragma unroll
    for (int i = 0; i < 4; ++i)
      af[i] = *(const bf16x8*)(&As[cur][(wm + i * 16 + lrow) * BK + quad * 8]);
#pragma unroll
    for (int j = 0; j < 4; ++j)
      bfr[j] = *(const bf16x8*)(&Bs[cur][(wn + j * 16 + lrow) * BK + quad * 8]);
#pragma unroll
    for (int i = 0; i < 4; ++i)
#pragma unroll
      for (int j = 0; j < 4; ++j)
        acc[i][j] = __builtin_amdgcn_mfma_f32_16x16x32_bf16(af[i], bfr[j], acc[i][j], 0, 0, 0);
    if (more && AF32) {
      bf16x8 a0, a1;
#pragma unroll
      for (int j = 0; j < 4; ++j) {
        a0[j] = (bf16_t)u0[j]; a0[j + 4] = (bf16_t)w0[j];
        a1[j] = (bf16_t)u1[j]; a1[j + 4] = (bf16_t)w1[j];
      }
      *(bf16x8*)(&As[nxt][r0 * BK + kc])        = a0;
      *(bf16x8*)(&As[nxt][(r0 + 64) * BK + kc]) = a1;
    }
    __syncthreads();
  }

  float*  Cf = (float*)Cv;
  bf16_t* Cb = (bf16_t*)Cv;
#pragma unroll
  for (int i = 0; i < 4; ++i) {
#pragma unroll
    for (int j = 0; j < 4; ++j) {
      int gn = n0 + wn + j * 16 + lrow;
      if (gn >= N) continue;
      float bv = bias ? bias[gn] : 0.f;
#pragma unroll
      for (int r = 0; r < 4; ++r) {
        int gm = m0 + wm + i * 16 + quad * 4 + r;
        if (gm >= M) continue;
        float v = acc[i][j][r] + bv;
        size_t ci = (size_t)gm * ldc + gn;
        if (MODE == MODE_F32)       Cf[ci] = v;
        else if (MODE == MODE_BF16) Cb[ci] = (bf16_t)v;
        else                        Cb[ci] = (bf16_t)(v > 0.f ? v : 0.f);
      }
    }
  }
}

// ---- merged offset+attn GEMM: A = (src+pos) inline; same 2-phase pipeline ----
__global__ __launch_bounds__(256) void gemm_qkv(
    const float* __restrict__ src, const float* __restrict__ pos,
    const bf16_t* __restrict__ Bt,     // wTqkv [480][256]
    const float* __restrict__ b_off, const float* __restrict__ b_attn,
    bf16_t* __restrict__ offb, float* __restrict__ attnb)
{
  __shared__ alignas(16) bf16_t As[2][BM * BK];
  __shared__ alignas(16) bf16_t Bs[2][BN * BK];
  const int tid  = threadIdx.x;
  const int wave = tid >> 6, lane = tid & 63;
  const int gid = xcd_swz(blockIdx.x, (int)gridDim.x);
  const int m0 = (gid >> 2) * BM;
  const int n0 = (gid & 3) * BN;
  const int wm = (wave & 1) * 64;
  const int wn = (wave >> 1) * 64;
  const int lrow = lane & 15;
  const int quad = lane >> 4;
  const int N = 480;

  const int srow = wave * 16 + (lane >> 2);
  const int scol = (lane & 3) * 8;
  const int br0 = min(n0 + srow,      N - 1);
  const int br1 = min(n0 + srow + 64, N - 1);
  const int r0 = tid >> 2;
  const int kc = (tid & 3) * 8;
  const int arw0 = min(m0 + r0,      M_ - 1);
  const int arw1 = min(m0 + r0 + 64, M_ - 1);

  auto stageB = [&](int ke, int buf) {
    gload_lds16(Bt + (size_t)br0 * 256 + ke + scol, &Bs[buf][wave * 512]);
    gload_lds16(Bt + (size_t)br1 * 256 + ke + scol, &Bs[buf][2048 + wave * 512]);
  };
  auto loadA = [&](int ke, f32x4& u0, f32x4& w0, f32x4& u1, f32x4& w1) {
    const f32x4* s0 = (const f32x4*)(src + (size_t)arw0 * 256 + ke + kc);
    const f32x4* p0 = (const f32x4*)(pos + (size_t)arw0 * 256 + ke + kc);
    const f32x4* s1 = (const f32x4*)(src + (size_t)arw1 * 256 + ke + kc);
    const f32x4* p1 = (const f32x4*)(pos + (size_t)arw1 * 256 + ke + kc);
    u0 = s0[0] + p0[0]; w0 = s0[1] + p0[1];
    u1 = s1[0] + p1[0]; w1 = s1[1] + p1[1];
  };
  auto writeA = [&](int buf, f32x4 u0, f32x4 w0, f32x4 u1, f32x4 w1) {
    bf16x8 a0, a1;
#pragma unroll
    for (int j = 0; j < 4; ++j) {
      a0[j] = (bf16_t)u0[j]; a0[j + 4] = (bf16_t)w0[j];
      a1[j] = (bf16_t)u1[j]; a1[j + 4] = (bf16_t)w1[j];
    }
    *(bf16x8*)(&As[buf][r0 * BK + kc])        = a0;
    *(bf16x8*)(&As[buf][(r0 + 64) * BK + kc]) = a1;
  };

  { f32x4 u0, w0, u1, w1; loadA(0, u0, w0, u1, w1); writeA(0, u0, w0, u1, w1); }
  stageB(0, 0);
  __syncthreads();

  f32x4 acc[4][4] = {};
  for (int kt = 0; kt < 8; ++kt) {
    const int cur = kt & 1, nxt = cur ^ 1;
    const bool more = kt < 7;
    f32x4 u0 = {}, w0 = {}, u1 = {}, w1 = {};
    if (more) { loadA((kt + 1) * BK, u0, w0, u1, w1); stageB((kt + 1) * BK, nxt); }
    bf16x8 af[4], bfr[4];
#pragma unroll
    for (int i = 0; i < 4; ++i)
      af[i] = *(const bf16x8*)(&As[cur][(wm + i * 16 + lrow) * BK + quad * 8]);
#pragma unroll
    for (int j = 0; j < 4; ++j)
      bfr[j] = *(const bf16x8*)(&Bs[cur][(wn + j * 16 + lrow) * BK + quad * 8]);
#pragma unroll
    for (int i = 0; i < 4; ++i)
#pragma unroll
      for (int j = 0; j < 4; ++j)
        acc[i][j] = __builtin_amdgcn_mfma_f32_16x16x32_bf16(af[i], bfr[j], acc[i][j], 0, 0, 0);
    if (more) writeA(nxt, u0, w0, u1, w1);
    __syncthreads();
  }

#pragma unroll
  for (int i = 0; i < 4; ++i) {
#pragma unroll
    for (int j = 0; j < 4; ++j) {
      int gn = n0 + wn + j * 16 + lrow;
      if (gn >= N) continue;
      float bv = (gn < 320) ? b_off[gn] : b_attn[gn - 320];
#pragma unroll
      for (int r = 0; r < 4; ++r) {
        int gm = m0 + wm + i * 16 + quad * 4 + r;
        if (gm >= M_) continue;
        float v = acc[i][j][r] + bv;
        if (gn < 320) offb[(size_t)gm * 320 + gn] = (bf16_t)v;
        else          attnb[(size_t)gm * 160 + gn - 320] = v;
      }
    }
  }
}

// ---------------- fused FFN, 2-phase pipelined ----------------
// 192 flattened steps (16 hc x (8 W1 + 4 W2)); stage(s+1) -> compute(s) -> barrier.
// Accumulation order and h bf16 rounding identical to unfused -> bit-identical.
__global__ __launch_bounds__(256) void k_ffn(
    const bf16_t* __restrict__ x,     // [M,256] bf16 (xbuf)
    const bf16_t* __restrict__ w1t,   // [2048][256]
    const float* __restrict__ bl1,    // [2048]
    const bf16_t* __restrict__ w2t,   // [256][2048]
    float* __restrict__ outf)         // [M,256] f32
{
  __shared__ alignas(16) bf16_t xs[8][64 * 32];     // 32KB
  __shared__ alignas(16) bf16_t hs[4][64 * 32];     // 16KB
  __shared__ alignas(16) bf16_t wst[2][256 * 32];   // 2 x 16KB (W1 uses first 8KB)
  const int tid  = threadIdx.x;
  const int wave = tid >> 6, lane = tid & 63;
  const int lrow = lane & 15, quad = lane >> 4;
  const int m0 = xcd_swz(blockIdx.x, (int)gridDim.x) * 64;
  const int srow = lane >> 2;
  const int scol = (lane & 3) * 8;
  const int wc0 = wave * 64;

  auto stage_w1 = [&](int hc, int kt, int buf) {
#pragma unroll
    for (int c = 0; c < 2; ++c) {
      int r = c * 64 + wave * 16 + srow;
      gload_lds16(w1t + (size_t)(hc * 128 + r) * 256 + kt * 32 + scol,
                  &wst[buf][c * 2048 + wave * 512]);
    }
  };
  auto stage_w2 = [&](int hc, int kt2, int buf) {
#pragma unroll
    for (int c = 0; c < 4; ++c) {
      int r = c * 64 + wave * 16 + srow;
      gload_lds16(w2t + (size_t)r * 2048 + hc * 128 + kt2 * 32 + scol,
                  &wst[buf][c * 2048 + wave * 512]);
    }
  };

  { // stage x (resident for all 16 hc) + first W1 tile
    int gr = min(m0 + wave * 16 + srow, M_ - 1);
#pragma unroll
    for (int c = 0; c < 8; ++c)
      gload_lds16(x + (size_t)gr * 256 + c * 32 + scol, &xs[c][wave * 512]);
  }
  stage_w1(0, 0, 0);
  __syncthreads();

  f32x4 cacc[4][4] = {};
  int s = 0;                       // flattened step counter (buffer parity)
  for (int hc = 0; hc < 16; ++hc) {
    float b0 = bl1[hc * 128 + wave * 32 + lrow];        // preload: hidden latency
    float b1 = bl1[hc * 128 + wave * 32 + 16 + lrow];
    f32x4 hacc[4][2] = {};
    for (int kt = 0; kt < 8; ++kt) {
      const int cur = s & 1, nxt = cur ^ 1;
      if (kt < 7) stage_w1(hc, kt + 1, nxt);
      else        stage_w2(hc, 0, nxt);
      bf16x8 af[4], bf[2];
#pragma unroll
      for (int i = 0; i < 4; ++i)
        af[i] = *(const bf16x8*)(&xs[kt][(i * 16 + lrow) * 32 + quad * 8]);
#pragma unroll
      for (int j = 0; j < 2; ++j)
        bf[j] = *(const bf16x8*)(&wst[cur][(wave * 32 + j * 16 + lrow) * 32 + quad * 8]);
#pragma unroll
      for (int i = 0; i < 4; ++i)
#pragma unroll
        for (int j = 0; j < 2; ++j)
          hacc[i][j] = __builtin_amdgcn_mfma_f32_16x16x32_bf16(af[i], bf[j], hacc[i][j], 0, 0, 0);
      if (kt == 7) {   // publish h (bias+relu, bf16) before this step's barrier
#pragma unroll
        for (int i = 0; i < 4; ++i)
#pragma unroll
          for (int j = 0; j < 2; ++j) {
            float bb = j ? b1 : b0;
#pragma unroll
            for (int r = 0; r < 4; ++r) {
              float v = hacc[i][j][r] + bb;
              hs[wave][(i * 16 + quad * 4 + r) * 32 + j * 16 + lrow] =
                  (bf16_t)(v > 0.f ? v : 0.f);
            }
          }
      }
      __syncthreads();
      ++s;
    }
    for (int kt2 = 0; kt2 < 4; ++kt2) {
      const int cur = s & 1, nxt = cur ^ 1;
      if (kt2 < 3)      stage_w2(hc, kt2 + 1, nxt);
      else if (hc < 15) stage_w1(hc + 1, 0, nxt);
      bf16x8 af2[4], bf2[4];
#pragma unroll
      for (int i = 0; i < 4; ++i)
        af2[i] = *(const bf16x8*)(&hs[kt2][(i * 16 + lrow) * 32 + quad * 8]);
#pragma unroll
      for (int j = 0; j < 4; ++j)
        bf2[j] = *(const bf16x8*)(&wst[cur][(wc0 + j * 16 + lrow) * 32 + quad * 8]);
#pragma unroll
      for (int i = 0; i < 4; ++i)
#pragma unroll
        for (int j = 0; j < 4; ++j)
          cacc[i][j] = __builtin_amdgcn_mfma_f32_16x16x32_bf16(af2[i], bf2[j], cacc[i][j], 0, 0, 0);
      __syncthreads();
      ++s;
    }
  }

#pragma unroll
  for (int i = 0; i < 4; ++i)
#pragma unroll
    for (int j = 0; j < 4; ++j)
#pragma unroll
      for (int r = 0; r < 4; ++r) {
        int gm = m0 + i * 16 + quad * 4 + r;
        if (gm < M_) outf[(size_t)gm * 256 + wc0 + j * 16 + lrow] = cacc[i][j][r];
      }
}

// ---------------- small kernels ----------------
__global__ __launch_bounds__(256) void k_transpose_all(
    const float* __restrict__ i0, const float* __restrict__ i1,
    const float* __restrict__ i2, const float* __restrict__ i3,
    const float* __restrict__ i4, const float* __restrict__ i5,
    bf16_t* __restrict__ o0, bf16_t* __restrict__ o1, bf16_t* __restrict__ o2,
    bf16_t* __restrict__ o3, bf16_t* __restrict__ o4, bf16_t* __restrict__ o5)
{
  int bid = blockIdx.x;
  const float* in; bf16_t* out; int K, N, txn;
  if (bid < 80)        { in = i0; out = o0; K = 256;  N = 320;  txn = 10; }
  else if (bid < 120)  { in = i1; out = o1; K = 256;  N = 160;  bid -= 80;  txn = 5; }
  else if (bid < 184)  { in = i2; out = o2; K = 256;  N = 256;  bid -= 120; txn = 8; }
  else if (bid < 248)  { in = i3; out = o3; K = 256;  N = 256;  bid -= 184; txn = 8; }
  else if (bid < 760)  { in = i4; out = o4; K = 256;  N = 2048; bid -= 248; txn = 64; }
  else                 { in = i5; out = o5; K = 2048; N = 256;  bid -= 760; txn = 8; }
  const int bx = bid % txn, by = bid / txn;
  __shared__ float tile[32][33];
  const int k0 = by * 32, n0 = bx * 32;
  const int tx = threadIdx.x & 31, ty = threadIdx.x >> 5;
#pragma unroll
  for (int r = ty; r < 32; r += 8)
    tile[r][tx] = in[(size_t)(k0 + r) * N + n0 + tx];
  __syncthreads();
#pragma unroll
  for (int r = ty; r < 32; r += 8)
    out[(size_t)(n0 + r) * K + k0 + tx] = (bf16_t)tile[tx][r];
}

// 8 queries/block; 32 threads/query; fused in-LDS softmax; XCD swizzle.
__global__ __launch_bounds__(256) void k_sample(
    const bf16_t* __restrict__ value,   // [B*LQ, 256]
    const bf16_t* __restrict__ off,     // [M, 320]
    const float* __restrict__ attn,     // [M, 160] RAW logits
    const float* __restrict__ rp,       // [M, 10]
    bf16_t* __restrict__ core)          // [M, 256]
{
  const int Wl[5] = {100, 50, 25, 13, 7};
  const int st[5] = {0, 10000, 12500, 13125, 13294};
  __shared__ alignas(16) bf16_t s_off[8][320];
  __shared__ alignas(16) float  s_attn[8][160];
  __shared__ float s_rp[8][10];
  const int t = threadIdx.x;
  const int bq0 = xcd_swz(blockIdx.x, (int)gridDim.x) * 8;
  for (int i = t; i < 320; i += 256) {
    int q = i / 40, e = i - q * 40;
    if (bq0 + q < M_) {
      *(bf16x8*)&s_off[q][e * 8] = *(const bf16x8*)(off + (size_t)(bq0 + q) * 320 + e * 8);
      *(f32x4*)&s_attn[q][e * 4] = *(const f32x4*)(attn + (size_t)(bq0 + q) * 160 + e * 4);
    }
  }
  if (t < 80) {
    int q = t / 10, e = t - q * 10;
    if (bq0 + q < M_) s_rp[q][e] = rp[(size_t)(bq0 + q) * 10 + e];
  }
  __syncthreads();
  if (t < 64) {
    float* p = &s_attn[t >> 3][(t & 7) * 20];
    float mx = p[0];
#pragma unroll
    for (int i = 1; i < 20; ++i) mx = fmaxf(mx, p[i]);
    float e[20], sum = 0.f;
#pragma unroll
    for (int i = 0; i < 20; ++i) { e[i] = expf(p[i] - mx); sum += e[i]; }
    float inv = 1.f / sum;
#pragma unroll
    for (int i = 0; i < 20; ++i) p[i] = e[i] * inv;
  }
  __syncthreads();

  const int wq = t >> 5, s = t & 31;
  const int h = s >> 2, d0 = (s & 3) * 8;
  const int bq = bq0 + wq;
  if (bq >= M_) return;
  const int b = bq / LQ_;
  const bf16_t* vbase = value + ((size_t)b * LQ_) * 256 + h * 32 + d0;
  float acc[8] = {};
#pragma unroll
  for (int lvl = 0; lvl < 5; ++lvl) {
    const float W = (float)Wl[lvl];
    const float rx = s_rp[wq][lvl * 2], ry = s_rp[wq][lvl * 2 + 1];
#pragma unroll
    for (int p = 0; p < 4; ++p) {
      const int base = (h * 5 + lvl) * 4 + p;
      float px = rx * W + (float)s_off[wq][base * 2]     - 0.5f;
      float py = ry * W + (float)s_off[wq][base * 2 + 1] - 0.5f;
      float aw = s_attn[wq][h * 20 + lvl * 4 + p];
      float x0f = floorf(px), y0f = floorf(py);
      float wx1 = px - x0f, wy1 = py - y0f;
      int x0 = (int)x0f, y0 = (int)y0f;
#pragma unroll
      for (int dy = 0; dy < 2; ++dy) {
        int yi = y0 + dy;
        bool vy = (yi >= 0) & (yi < Wl[lvl]);
        int yc = min(max(yi, 0), Wl[lvl] - 1);
        float wy = dy ? wy1 : 1.f - wy1;
#pragma unroll
        for (int dx = 0; dx < 2; ++dx) {
          int xi = x0 + dx;
          bool vx = (xi >= 0) & (xi < Wl[lvl]);
          int xc = min(max(xi, 0), Wl[lvl] - 1);
          float cw = (vx & vy) ? aw * wy * (dx ? wx1 : 1.f - wx1) : 0.f;
          bf16x8 v = *(const bf16x8*)(vbase + (size_t)(st[lvl] + yc * Wl[lvl] + xc) * 256);
#pragma unroll
          for (int j = 0; j < 8; ++j) acc[j] += cw * (float)v[j];
        }
      }
    }
  }
  bf16x8 o;
#pragma unroll
  for (int j = 0; j < 8; ++j) o[j] = (bf16_t)acc[j];
  *(bf16x8*)(core + (size_t)bq * 256 + h * 32 + d0) = o;
}

// out = LN(a + res [+ eb]) * g + beta ; one row per wave
template <typename TA, typename TR, typename TO>
__global__ __launch_bounds__(256) void k_ln4(
    const TA* __restrict__ a, const TR* __restrict__ res,
    const float* __restrict__ eb, const float* __restrict__ g,
    const float* __restrict__ beta, TO* __restrict__ out, int rows)
{
  const int wave = threadIdx.x >> 6, lane = threadIdx.x & 63;
  const int row = blockIdx.x * 4 + wave;
  if (row >= rows) return;
  const size_t base = (size_t)row * 256 + lane * 4;
  float v[4];
#pragma unroll
  for (int j = 0; j < 4; ++j) {
    v[j] = (float)a[base + j] + (float)res[base + j];
    if (eb) v[j] += eb[lane * 4 + j];
  }
  float s1 = v[0] + v[1] + v[2] + v[3];
  float s2 = v[0] * v[0] + v[1] * v[1] + v[2] * v[2] + v[3] * v[3];
#pragma unroll
  for (int o = 32; o > 0; o >>= 1) { s1 += __shfl_xor(s1, o); s2 += __shfl_xor(s2, o); }
  float m = s1 * (1.f / 256.f);
  float var = s2 * (1.f / 256.f) - m * m;
  float inv = rsqrtf(var + 1e-5f);
#pragma unroll
  for (int j = 0; j < 4; ++j)
    out[base + j] = (TO)(((v[j] - m) * inv) * g[lane * 4 + j] + beta[lane * 4 + j]);
}

// ---------------- launcher ----------------
extern "C" void kernel_launch(void* const* d_in, const int* in_sizes, int n_in,
                              void* d_out, int out_size, void* d_ws, size_t ws_size,
                              hipStream_t stream) {
  const float* src   = (const float*)d_in[0];
  const float* pos   = (const float*)d_in[1];
  const float* rp    = (const float*)d_in[2];
  const float* W_off = (const float*)d_in[5];
  const float* b_off = (const float*)d_in[6];
  const float* W_attn= (const float*)d_in[7];
  const float* b_attn= (const float*)d_in[8];
  const float* W_val = (const float*)d_in[9];
  const float* b_val = (const float*)d_in[10];
  const float* W_out = (const float*)d_in[11];
  const float* b_out = (const float*)d_in[12];
  const float* g1    = (const float*)d_in[13];
  const float* beta1 = (const float*)d_in[14];
  const float* W1    = (const float*)d_in[15];
  const float* bl1   = (const float*)d_in[16];
  const float* W2    = (const float*)d_in[17];
  const float* bl2   = (const float*)d_in[18];
  const float* g2    = (const float*)d_in[19];
  const float* beta2 = (const float*)d_in[20];

  char* ws = (char*)d_ws;
  const size_t SZ_TOK = (size_t)M_ * 256 * 2;  // 27,326,464
  const size_t SZ_ATT = (size_t)M_ * 160 * 4;  // 34,158,080

  size_t o = 0;
  bf16_t* wTqkv = (bf16_t*)(ws + o); o += 480 * 256 * 2;
  bf16_t* wTval = (bf16_t*)(ws + o); o += 256 * 256 * 2;
  bf16_t* wTout = (bf16_t*)(ws + o); o += 256 * 256 * 2;
  bf16_t* wT1   = (bf16_t*)(ws + o); o += 2048 * 256 * 2;
  bf16_t* wT2   = (bf16_t*)(ws + o); o += 2048 * 256 * 2;
  o = (o + 255) & ~(size_t)255;
  char* Areg = ws + o; o += SZ_TOK;   // coreb
  char* Creg = ws + o; o += SZ_ATT;   // attnb -> attn_out
  char* Dreg = ws + o; o += SZ_TOK;   // valb -> xbuf

  bf16_t* coreb   = (bf16_t*)Areg;
  float*  attnb   = (float*) Creg;
  bf16_t* attn_out= (bf16_t*)Creg;
  bf16_t* valb    = (bf16_t*)Dreg;
  bf16_t* xbuf    = (bf16_t*)Dreg;
  bf16_t* offb    = (bf16_t*)d_out;   // dead before k_ffn writes outf
  float*  outf    = (float*) d_out;

  k_transpose_all<<<dim3(1272), 256, 0, stream>>>(
      W_off, W_attn, W_val, W_out, W1, W2,
      wTqkv, wTqkv + 320 * 256, wTval, wTout, wT1, wT2);

  dim3 blk(256);
  const int gM = (M_ + BM - 1) / BM;   // 417

  gemm_qkv<<<dim3(gM * 4), blk, 0, stream>>>(src, pos, wTqkv, b_off, b_attn, offb, attnb);
  gemm_bt<MODE_BF16, true><<<dim3(gM * 2), blk, 0, stream>>>(src, 256, wTval, 256, b_val, valb, 256, M_, 256, 256);
  k_sample<<<dim3((M_ + 7) / 8), blk, 0, stream>>>(valb, offb, attnb, rp, coreb);
  gemm_bt<MODE_BF16, false><<<dim3(gM * 2), blk, 0, stream>>>(coreb, 256, wTout, 256, b_out, attn_out, 256, M_, 256, 256);
  k_ln4<float, bf16_t, bf16_t><<<dim3((M_ + 3) / 4), blk, 0, stream>>>(src, attn_out, (const float*)nullptr, g1, beta1, xbuf, M_);

  k_ffn<<<dim3((M_ + 63) / 64), blk, 0, stream>>>(xbuf, wT1, bl1, wT2, outf);

  k_ln4<bf16_t, float, float><<<dim3((M_ + 3) / 4), blk, 0, stream>>>(xbuf, outf, bl2, g2, beta2, outf, M_);
}